// Round 8
// baseline (119.126 us; speedup 1.0000x reference)
//
#include <hip/hip_runtime.h>

typedef float v2f __attribute__((ext_vector_type(2)));

// ---------------------------------------------------------------------------
// Cross-lane helpers. Gates need masks 1,2,8 (DPP) and 4,16 (ds_swizzle,
// group-contained within 32 lanes); ds_bpermute only for the angle gather.
// ---------------------------------------------------------------------------
template<int C>
__device__ __forceinline__ float dppmov(float x) {
  return __int_as_float(__builtin_amdgcn_update_dpp(0, __float_as_int(x), C, 0xF, 0xF, true));
}
template<int IMM>
__device__ __forceinline__ float dswz(float x) {
  return __int_as_float(__builtin_amdgcn_ds_swizzle(__float_as_int(x), IMM));
}
__device__ __forceinline__ float bperm(float x, int a) {
  return __int_as_float(__builtin_amdgcn_ds_bpermute(a, __float_as_int(x)));
}
template<int M>
__device__ __forceinline__ float bfly(float x) {
  if constexpr (M == 1)       return dppmov<0xB1>(x);   // quad_perm [1,0,3,2]
  else if constexpr (M == 2)  return dppmov<0x4E>(x);   // quad_perm [2,3,0,1]
  else if constexpr (M == 8)  return dppmov<0x128>(x);  // row_ror:8 == xor8
  else if constexpr (M == 4)  return dswz<0x101F>(x);   // bit-mode xor4
  else                        return dswz<0x401F>(x);   // M==16: bit-mode xor16
}
template<int M>
__device__ __forceinline__ v2f bfly2(v2f v) {
  v2f o; o.x = bfly<M>(v.x); o.y = bfly<M>(v.y); return o;
}
__device__ __forceinline__ v2f sp(float s) { v2f v; v.x = s; v.y = s; return v; }
__device__ __forceinline__ v2f vfma(v2f a, v2f b, v2f c) {
  return __builtin_elementwise_fma(a, b, c);
}

// ---------------------------------------------------------------------------
// Layout: 4 pixels/wave. Lane-group g = lane>>5 (32 lanes) holds the packed
// pixel pair (p0+2g, p0+2g+1) in v2f. Amp i = q*8 + r, q = lane&31, r = 0..7.
// Wire 0..4 <-> q bits 4..0 (masks 16,8,4,2,1); wires 5..7 <-> r bits 2..0.
// ---------------------------------------------------------------------------
template<int M, int CM>
__device__ __forceinline__ void crossG(v2f Sr[8], v2f Si[8],
    const float* __restrict__ g, int lane) {
  const bool hi = (lane & M) != 0;
  float fr, fi, gr, gi;
  if constexpr (CM == 0) {
    fr = hi ? g[6] : g[0]; fi = hi ? g[7] : g[1];
    gr = hi ? g[4] : g[2]; gi = hi ? g[5] : g[3];
  } else {
    const bool ct = (lane & CM) != 0;
    float f0r = hi ? g[6]  : g[0],  f0i = hi ? g[7]  : g[1];
    float g0r = hi ? g[4]  : g[2],  g0i = hi ? g[5]  : g[3];
    float f1r = hi ? g[14] : g[8],  f1i = hi ? g[15] : g[9];
    float g1r = hi ? g[12] : g[10], g1i = hi ? g[13] : g[11];
    fr = ct ? f1r : f0r; fi = ct ? f1i : f0i;
    gr = ct ? g1r : g0r; gi = ct ? g1i : g0i;
  }
  v2f vfr = sp(fr), vfi = sp(fi), vgr = sp(gr), vgi = sp(gi);
  v2f vfiN = sp(-fi), vgiN = sp(-gi);
#pragma unroll
  for (int r = 0; r < 8; ++r) {
    v2f pR = bfly2<M>(Sr[r]);
    v2f pI = bfly2<M>(Si[r]);
    v2f nR = vfma(vgiN, pI, vfma(vgr, pR, vfma(vfiN, Si[r], vfr * Sr[r])));
    v2f nI = vfma(vgi,  pR, vfma(vgr, pI, vfma(vfi,  Sr[r], vfr * Si[r])));
    Sr[r] = nR; Si[r] = nI;
  }
}

__device__ __forceinline__ void mixP(v2f& x0r, v2f& x0i, v2f& x1r, v2f& x1i,
    float m0r, float m0i, float m1r, float m1i,
    float m2r, float m2i, float m3r, float m3i) {
  v2f n0r = vfma(sp(-m1i), x1i, vfma(sp(m1r), x1r, vfma(sp(-m0i), x0i, sp(m0r) * x0r)));
  v2f n0i = vfma(sp( m1i), x1r, vfma(sp(m1r), x1i, vfma(sp( m0i), x0r, sp(m0r) * x0i)));
  v2f n1r = vfma(sp(-m3i), x1i, vfma(sp(m3r), x1r, vfma(sp(-m2i), x0i, sp(m2r) * x0r)));
  v2f n1i = vfma(sp( m3i), x1r, vfma(sp(m3r), x1i, vfma(sp( m2i), x0r, sp(m2r) * x0i)));
  x0r = n0r; x0i = n0i; x1r = n1r; x1i = n1i;
}

// F5: fused u3(w5)+cu3(4->5): ctrl lane bit0 (runtime), target r bit2.
__device__ __forceinline__ void f5N(v2f Sr[8], v2f Si[8],
    const float* __restrict__ g, int lane) {
  const bool ct = (lane & 1) != 0;
  float m[8];
#pragma unroll
  for (int jj = 0; jj < 8; ++jj) m[jj] = ct ? g[8 + jj] : g[jj];
#pragma unroll
  for (int r = 0; r < 4; ++r)
    mixP(Sr[r], Si[r], Sr[r + 4], Si[r + 4],
         m[0], m[1], m[2], m[3], m[4], m[5], m[6], m[7]);
}
// F6: ctrl r bit2 (compile-time), target r bit1.
__device__ __forceinline__ void f6N(v2f Sr[8], v2f Si[8],
    const float* __restrict__ g) {
  mixP(Sr[0], Si[0], Sr[2], Si[2], g[0],g[1],g[2],g[3],g[4],g[5],g[6],g[7]);
  mixP(Sr[1], Si[1], Sr[3], Si[3], g[0],g[1],g[2],g[3],g[4],g[5],g[6],g[7]);
  mixP(Sr[4], Si[4], Sr[6], Si[6], g[8],g[9],g[10],g[11],g[12],g[13],g[14],g[15]);
  mixP(Sr[5], Si[5], Sr[7], Si[7], g[8],g[9],g[10],g[11],g[12],g[13],g[14],g[15]);
}
// F7: ctrl r bit1, target r bit0.
__device__ __forceinline__ void f7N(v2f Sr[8], v2f Si[8],
    const float* __restrict__ g) {
  mixP(Sr[0], Si[0], Sr[1], Si[1], g[0],g[1],g[2],g[3],g[4],g[5],g[6],g[7]);
  mixP(Sr[4], Si[4], Sr[5], Si[5], g[0],g[1],g[2],g[3],g[4],g[5],g[6],g[7]);
  mixP(Sr[2], Si[2], Sr[3], Si[3], g[8],g[9],g[10],g[11],g[12],g[13],g[14],g[15]);
  mixP(Sr[6], Si[6], Sr[7], Si[7], g[8],g[9],g[10],g[11],g[12],g[13],g[14],g[15]);
}
// F8': fused cu3(7->0)+next u3(w0): ctrl r bit0, target lane mask 16.
__device__ __forceinline__ void f8pN(v2f Sr[8], v2f Si[8],
    const float* __restrict__ g, int lane) {
  const bool hi = (lane & 16) != 0;
  float fr[2], fi[2], gr[2], gi[2];
  fr[0] = hi ? g[6]  : g[0];  fi[0] = hi ? g[7]  : g[1];
  gr[0] = hi ? g[4]  : g[2];  gi[0] = hi ? g[5]  : g[3];
  fr[1] = hi ? g[14] : g[8];  fi[1] = hi ? g[15] : g[9];
  gr[1] = hi ? g[12] : g[10]; gi[1] = hi ? g[13] : g[11];
#pragma unroll
  for (int r = 0; r < 8; ++r) {
    const int m = r & 1;
    v2f pR = bfly2<16>(Sr[r]);
    v2f pI = bfly2<16>(Si[r]);
    v2f nR = vfma(sp(-gi[m]), pI, vfma(sp(gr[m]), pR, vfma(sp(-fi[m]), Si[r], sp(fr[m]) * Sr[r])));
    v2f nI = vfma(sp( gi[m]), pR, vfma(sp(gr[m]), pI, vfma(sp( fi[m]), Sr[r], sp(fr[m]) * Si[r])));
    Sr[r] = nR; Si[r] = nI;
  }
}
// F8 final standalone cu3(7->0): odd r only, target mask 16.
__device__ __forceinline__ void f8N(v2f Sr[8], v2f Si[8],
    const float* __restrict__ g, int lane) {
  const bool hi = (lane & 16) != 0;
  const float fr = hi ? g[6] : g[0], fi = hi ? g[7] : g[1];
  const float gr = hi ? g[4] : g[2], gi = hi ? g[5] : g[3];
#pragma unroll
  for (int r = 1; r < 8; r += 2) {
    v2f pR = bfly2<16>(Sr[r]);
    v2f pI = bfly2<16>(Si[r]);
    v2f nR = vfma(sp(-gi), pI, vfma(sp(gr), pR, vfma(sp(-fi), Si[r], sp(fr) * Sr[r])));
    v2f nI = vfma(sp( gi), pR, vfma(sp(gr), pI, vfma(sp( fi), Sr[r], sp(fr) * Si[r])));
    Sr[r] = nR; Si[r] = nI;
  }
}

// Unnormalized Hadamard on all 8 wires (scale folded into FC weights).
template<int M>
__device__ __forceinline__ void hstepN(v2f Sr[8], v2f Si[8], float sgn) {
  v2f s = sp(sgn);
#pragma unroll
  for (int r = 0; r < 8; ++r) {
    v2f pR = bfly2<M>(Sr[r]);
    v2f pI = bfly2<M>(Si[r]);
    Sr[r] = vfma(s, Sr[r], pR);
    Si[r] = vfma(s, Si[r], pI);
  }
}
__device__ __forceinline__ void hp(v2f& a, v2f& b) { v2f t = a; a = t + b; b = t - b; }
__device__ __forceinline__ void hintraN(v2f S[8]) {
  hp(S[0],S[4]); hp(S[1],S[5]); hp(S[2],S[6]); hp(S[3],S[7]);
  hp(S[0],S[2]); hp(S[1],S[3]); hp(S[4],S[6]); hp(S[5],S[7]);
  hp(S[0],S[1]); hp(S[2],S[3]); hp(S[4],S[5]); hp(S[6],S[7]);
}
__device__ __forceinline__ void hallN(v2f Sr[8], v2f Si[8], const float* sg) {
  hstepN<16>(Sr, Si, sg[0]);
  hstepN<8>(Sr, Si, sg[1]);
  hstepN<4>(Sr, Si, sg[2]);
  hstepN<2>(Sr, Si, sg[3]);
  hstepN<1>(Sr, Si, sg[4]);
  hintraN(Sr); hintraN(Si);
}

// diag(1,-i) on every wire: amp i *= (-i)^popc(i), popc(i)=popc(q)+popc(r).
__device__ __forceinline__ void phaseYN(v2f Sr[8], v2f Si[8], int lane) {
  const int pl = __popc(lane & 31);
#pragma unroll
  for (int r = 0; r < 8; ++r) {
    const int qq = (pl + __popc(r)) & 3;
    const bool b0 = (qq & 1) != 0;
    const bool b1 = (qq & 2) != 0;
    const float sR = b1 ? -1.0f : 1.0f;
    const float sI = (b0 != b1) ? -1.0f : 1.0f;
    v2f Rs = b0 ? Si[r] : Sr[r];
    v2f Is = b0 ? Sr[r] : Si[r];
    Sr[r] = sp(sR) * Rs;
    Si[r] = sp(sI) * Is;
  }
}

// <Z_w> for the group's packed pair: 8 pre-signed chains, 5-step butterfly
// sums over the 32-lane group -> all 8 marginals group-uniform (v2f).
__device__ __forceinline__ void measureN(const v2f Sr[8], const v2f Si[8],
    const float* sg, v2f m[8]) {
  v2f P[8];
#pragma unroll
  for (int r = 0; r < 8; ++r) P[r] = vfma(Si[r], Si[r], Sr[r] * Sr[r]);
  v2f d7 = (P[0] - P[1]) + (P[2] - P[3]) + (P[4] - P[5]) + (P[6] - P[7]);
  v2f t0 = P[0] + P[1], t1 = P[2] + P[3], t2 = P[4] + P[5], t3 = P[6] + P[7];
  v2f d6 = (t0 - t1) + (t2 - t3);
  v2f q0 = t0 + t1, q1 = t2 + t3;
  v2f d5 = q0 - q1;
  v2f pa = q0 + q1;
  v2f c0 = sp(sg[0]) * pa, c1 = sp(sg[1]) * pa, c2 = sp(sg[2]) * pa;
  v2f c3 = sp(sg[3]) * pa, c4 = sp(sg[4]) * pa;
  v2f c5 = d5, c6 = d6, c7 = d7;
#define BSUM(M) \
  c0 = c0 + bfly2<M>(c0); c1 = c1 + bfly2<M>(c1); \
  c2 = c2 + bfly2<M>(c2); c3 = c3 + bfly2<M>(c3); \
  c4 = c4 + bfly2<M>(c4); c5 = c5 + bfly2<M>(c5); \
  c6 = c6 + bfly2<M>(c6); c7 = c7 + bfly2<M>(c7);
  BSUM(1) BSUM(2) BSUM(4) BSUM(8) BSUM(16)
#undef BSUM
  m[0] = c0; m[1] = c1; m[2] = c2; m[3] = c3;
  m[4] = c4; m[5] = c5; m[6] = c6; m[7] = c7;
}

// FC fold: lane handles pixel (.x/.y by q bit4) and channels 2j, 2j+1.
__device__ __forceinline__ void fcN(const v2f m[8],
    const float* __restrict__ wbase, bool isB, int j, float acc[2]) {
  float mm[8];
#pragma unroll
  for (int w = 0; w < 8; ++w) mm[w] = isB ? m[w].y : m[w].x;
#pragma unroll
  for (int k = 0; k < 2; ++k) {
    const float4* w4 = reinterpret_cast<const float4*>(wbase + (2 * j + k) * 8);
    float4 a = w4[0], b = w4[1];
    float s = acc[k];
    s = fmaf(mm[0], a.x, s); s = fmaf(mm[1], a.y, s);
    s = fmaf(mm[2], a.z, s); s = fmaf(mm[3], a.w, s);
    s = fmaf(mm[4], b.x, s); s = fmaf(mm[5], b.y, s);
    s = fmaf(mm[6], b.z, s); s = fmaf(mm[7], b.w, s);
    acc[k] = s;
  }
}

// ---------------------------------------------------------------------------
// Prep (identical G table to rounds 3-7; fusion matrices are position-based).
// ---------------------------------------------------------------------------
__device__ __forceinline__ void mm2(const float* A, const float* B, float* D) {
  D[0] = A[0]*B[0] - A[1]*B[1] + A[2]*B[4] - A[3]*B[5];
  D[1] = A[0]*B[1] + A[1]*B[0] + A[2]*B[5] + A[3]*B[4];
  D[2] = A[0]*B[2] - A[1]*B[3] + A[2]*B[6] - A[3]*B[7];
  D[3] = A[0]*B[3] + A[1]*B[2] + A[2]*B[7] + A[3]*B[6];
  D[4] = A[4]*B[0] - A[5]*B[1] + A[6]*B[4] - A[7]*B[5];
  D[5] = A[4]*B[1] + A[5]*B[0] + A[6]*B[5] + A[7]*B[4];
  D[6] = A[4]*B[2] - A[5]*B[3] + A[6]*B[6] - A[7]*B[7];
  D[7] = A[4]*B[3] + A[5]*B[2] + A[6]*B[7] + A[7]*B[6];
}
__device__ __forceinline__ void u3fill(const float* src, float* o) {
  float th = src[0], ph = src[1], lam = src[2];
  float c = cosf(0.5f * th), s = sinf(0.5f * th);
  float cl = cosf(lam), sl = sinf(lam);
  float cp = cosf(ph), spv = sinf(ph);
  float cpl = cosf(ph + lam), spl = sinf(ph + lam);
  o[0] = c;        o[1] = 0.0f;
  o[2] = -cl * s;  o[3] = -sl * s;
  o[4] = cp * s;   o[5] = spv * s;
  o[6] = cpl * c;  o[7] = spl * c;
}

__global__ __launch_bounds__(128) void prep_kernel(
    const float* __restrict__ u3p, const float* __restrict__ cu3p,
    const float* __restrict__ fcw, float* __restrict__ G,
    float* __restrict__ FCW2) {
  __shared__ float Us[40][8];
  __shared__ float Cs[40][8];
  int t = threadIdx.x;
  if (t < 40) u3fill(u3p + t * 3, Us[t]);
  if (t >= 64 && t < 104) u3fill(cu3p + (t - 64) * 3, Cs[t - 64]);
  __syncthreads();
  if (t == 0) {
#pragma unroll
    for (int j = 0; j < 8; ++j) G[j] = Us[0][j];
  } else if (t < 36) {
    int j = t - 1, b = j / 7, k = j % 7;
    float* dst = G + 8 + b * 112 + k * 16;
    const float* U = Us[b * 8 + k + 1];
    const float* C = Cs[b * 8 + k];
#pragma unroll
    for (int q = 0; q < 8; ++q) dst[q] = U[q];
    mm2(C, U, dst + 8);
  } else if (t < 40) {
    int b = t - 36;
    float* dst = G + 568 + b * 16;
    const float* U = Us[(b + 1) * 8];
    const float* C = Cs[b * 8 + 7];
#pragma unroll
    for (int q = 0; q < 8; ++q) dst[q] = U[q];
    mm2(U, C, dst + 8);
  } else if (t == 40) {
#pragma unroll
    for (int j = 0; j < 8; ++j) G[632 + j] = Cs[39][j];
  }
  for (int i = t; i < 768; i += 128) {
    int s = i >> 8, cc = (i >> 3) & 31, wv = i & 7;
    float sc = (s == 0) ? 1.0f : ((s == 1) ? (1.0f / 256.0f) : (1.0f / 65536.0f));
    FCW2[i] = fcw[cc * 24 + s * 8 + wv] * sc;
  }
}

// ---------------------------------------------------------------------------
// Fused conv + qsim, 4 px/wave, pixel-pair-per-32-lanes layout.
// ---------------------------------------------------------------------------
__global__ __launch_bounds__(256) void qconv_kernel(
    const float* __restrict__ x, const float* __restrict__ cw,
    const float* __restrict__ cb, const float* __restrict__ G,
    const float* __restrict__ FCW2, const float* __restrict__ fcb,
    float* __restrict__ out) {
  const int lane = threadIdx.x & 63;
  const int wid = __builtin_amdgcn_readfirstlane(
      (int)((blockIdx.x * blockDim.x + threadIdx.x) >> 6));
  const int p0 = wid * 4;
  const int q = lane & 31;

  float sg[5];
  sg[0] = (q & 16) ? -1.0f : 1.0f;
  sg[1] = (q & 8)  ? -1.0f : 1.0f;
  sg[2] = (q & 4)  ? -1.0f : 1.0f;
  sg[3] = (q & 2)  ? -1.0f : 1.0f;
  sg[4] = (q & 1)  ? -1.0f : 1.0f;

  // ---- conv: lane = (px = lane>>4, oc = (lane>>1)&7, icg = lane&1) ----
  float ang;
  {
    const int icg = lane & 1;
    const int oc  = (lane >> 1) & 7;
    const int px  = lane >> 4;
    const int p   = p0 + px;
    const int b   = p >> 12;
    const int hh  = (p >> 6) & 63;
    const int wim = p & 63;
    float acc = 0.0f;
#pragma unroll 2
    for (int il = 0; il < 8; ++il) {
      const int ic = icg * 8 + il;
      const float* wp = cw + (oc * 16 + ic) * 9;
      const float* xp = x + (b * 16 + ic) * 4096;
#pragma unroll
      for (int kh = 0; kh < 3; ++kh) {
        int ih = hh + kh - 1;
        bool rok = (unsigned)ih < 64u;
        int ihc = rok ? ih : 0;
#pragma unroll
        for (int kw = 0; kw < 3; ++kw) {
          int iw = wim + kw - 1;
          bool ok = rok && ((unsigned)iw < 64u);
          int iwc = ((unsigned)iw < 64u) ? iw : 0;
          float xv = xp[ihc * 64 + iwc];
          acc = fmaf(ok ? xv : 0.0f, wp[kh * 3 + kw], acc);
        }
      }
    }
    acc += bfly<1>(acc);     // reduce over icg
    ang = acc + cb[oc];
  }

  // ---- gather group's 16 angles via bpermute, build packed product state ----
  v2f Sr[8], Si[8];
  {
    const int gb = lane & 32;  // group base lane
    float aA[8], aB[8];
#pragma unroll
    for (int w = 0; w < 8; ++w) {
      aA[w] = bperm(ang, (gb + 2 * w) << 2);        // px A (px index 2g)
      aB[w] = bperm(ang, (gb + 16 + 2 * w) << 2);   // px B (px index 2g+1)
    }
    float cA[8], sA[8], cB[8], sB[8];
#pragma unroll
    for (int w = 0; w < 8; ++w) {
      __sincosf(0.5f * aA[w], &sA[w], &cA[w]);
      __sincosf(0.5f * aB[w], &sB[w], &cB[w]);
    }
    float fA = ((q & 16) ? sA[0] : cA[0]) * ((q & 8) ? sA[1] : cA[1])
             * ((q & 4) ? sA[2] : cA[2]) * ((q & 2) ? sA[3] : cA[3])
             * ((q & 1) ? sA[4] : cA[4]);
    float fB = ((q & 16) ? sB[0] : cB[0]) * ((q & 8) ? sB[1] : cB[1])
             * ((q & 4) ? sB[2] : cB[2]) * ((q & 2) ? sB[3] : cB[3])
             * ((q & 1) ? sB[4] : cB[4]);
    v2f uu[4], vv[2];
    uu[0].x = cA[6]*cA[7]; uu[1].x = cA[6]*sA[7];
    uu[2].x = sA[6]*cA[7]; uu[3].x = sA[6]*sA[7];
    uu[0].y = cB[6]*cB[7]; uu[1].y = cB[6]*sB[7];
    uu[2].y = sB[6]*cB[7]; uu[3].y = sB[6]*sB[7];
    vv[0].x = fA * cA[5]; vv[1].x = fA * sA[5];
    vv[0].y = fB * cB[5]; vv[1].y = fB * sB[5];
#pragma unroll
    for (int r = 0; r < 8; ++r) {
      Sr[r] = vv[r >> 2] * uu[r & 3];
      Si[r] = sp(0.0f);
    }
  }

  // ---- fused circuit (same G table as round 3, remapped wire roles) ----
  crossG<16, 0>(Sr, Si, G, lane);            // F0 = U[0][0] on wire 0
  for (int b = 0; b < 5; ++b) {
    const float* base = G + 8 + b * 112;
    crossG<8, 16>(Sr, Si, base +  0, lane);  // F1: ctrl w0, tgt w1
    crossG<4, 8> (Sr, Si, base + 16, lane);  // F2
    crossG<2, 4> (Sr, Si, base + 32, lane);  // F3
    crossG<1, 2> (Sr, Si, base + 48, lane);  // F4
    f5N(Sr, Si, base + 64, lane);            // F5: ctrl lane bit0, tgt r bit2
    f6N(Sr, Si, base + 80);                  // F6
    f7N(Sr, Si, base + 96);                  // F7
    if (b < 4) f8pN(Sr, Si, G + 568 + b * 16, lane);
  }
  f8N(Sr, Si, G + 632, lane);

  // ---- three measurement stages folded into FC ----
  const int j = q & 15;
  const bool isB = (q & 16) != 0;
  float acc[2];
  acc[0] = fcb[2 * j];
  acc[1] = fcb[2 * j + 1];

  v2f m[8];
  measureN(Sr, Si, sg, m);
  fcN(m, FCW2, isB, j, acc);
  hallN(Sr, Si, sg);
  measureN(Sr, Si, sg, m);
  fcN(m, FCW2 + 256, isB, j, acc);
  phaseYN(Sr, Si, lane);
  hallN(Sr, Si, sg);
  measureN(Sr, Si, sg, m);
  fcN(m, FCW2 + 512, isB, j, acc);

  // ---- store: pixel p0 + 2g + isB, channels 2j, 2j+1 ----
  const int g = lane >> 5;
  const int p = p0 + 2 * g + (isB ? 1 : 0);
  const int ob = (p >> 12) * 131072 + (p & 4095);
  out[ob + (2 * j) * 4096]     = acc[0];
  out[ob + (2 * j + 1) * 4096] = acc[1];
}

extern "C" void kernel_launch(void* const* d_in, const int* in_sizes, int n_in,
                              void* d_out, int out_size, void* d_ws, size_t ws_size,
                              hipStream_t stream) {
  const float* x      = (const float*)d_in[0];
  const float* conv_w = (const float*)d_in[1];
  const float* conv_b = (const float*)d_in[2];
  const float* u3p    = (const float*)d_in[3];
  const float* cu3p   = (const float*)d_in[4];
  const float* fcw    = (const float*)d_in[5];
  const float* fcb    = (const float*)d_in[6];
  float* out = (float*)d_out;

  float* ws   = (float*)d_ws;
  float* G    = ws;          // 640 (fused gate matrices)
  float* FCW2 = ws + 640;    // 768 (stage-major, pre-scaled)

  prep_kernel<<<1, 128, 0, stream>>>(u3p, cu3p, fcw, G, FCW2);
  qconv_kernel<<<1024, 256, 0, stream>>>(x, conv_w, conv_b, G, FCW2, fcb, out);
}

// Round 10
// 114.466 us; speedup vs baseline: 1.0407x; 1.0407x over previous
//
#include <hip/hip_runtime.h>

typedef float v2f __attribute__((ext_vector_type(2)));

// ---------------------------------------------------------------------------
// Cross-lane helpers (r7 layout): masks 1,2,8 via DPP (VALU pipe), mask 4 via
// ds_swizzle; ds_bpermute only for the one-time angle gather.
// ---------------------------------------------------------------------------
template<int C>
__device__ __forceinline__ float dppmov(float x) {
  return __int_as_float(__builtin_amdgcn_update_dpp(0, __float_as_int(x), C, 0xF, 0xF, true));
}
template<int IMM>
__device__ __forceinline__ float dswz(float x) {
  return __int_as_float(__builtin_amdgcn_ds_swizzle(__float_as_int(x), IMM));
}
__device__ __forceinline__ float bperm(float x, int a) {
  return __int_as_float(__builtin_amdgcn_ds_bpermute(a, __float_as_int(x)));
}
template<int M>
__device__ __forceinline__ float bfly(float x) {
  if constexpr (M == 1)      return dppmov<0xB1>(x);   // quad_perm [1,0,3,2]
  else if constexpr (M == 2) return dppmov<0x4E>(x);   // quad_perm [2,3,0,1]
  else if constexpr (M == 8) return dppmov<0x128>(x);  // row_ror:8 == xor8
  else                       return dswz<0x101F>(x);   // M==4: bit-mode xor4
}
template<int M>
__device__ __forceinline__ v2f bfly2(v2f v) {
  v2f o; o.x = bfly<M>(v.x); o.y = bfly<M>(v.y); return o;
}
__device__ __forceinline__ v2f sp(float s) { v2f v; v.x = s; v.y = s; return v; }
__device__ __forceinline__ v2f vfma(v2f a, v2f b, v2f c) {
  return __builtin_elementwise_fma(a, b, c);
}

// ---------------------------------------------------------------------------
// Layout: 8 pixels/wave. Group g = lane>>4 holds the packed pixel pair in v2f.
// Amp i = q*16 + r, q = lane&15, r = 0..15. Wires 0..3 <-> q bits 3..0
// (masks 8,4,2,1); wires 4..7 <-> r bits 3..0.
// ---------------------------------------------------------------------------
template<int M, int CM>
__device__ __forceinline__ void crossG(v2f Sr[16], v2f Si[16],
    const float* __restrict__ g, int lane) {
  const bool hi = (lane & M) != 0;
  float fr, fi, gr, gi;
  if constexpr (CM == 0) {
    fr = hi ? g[6] : g[0]; fi = hi ? g[7] : g[1];
    gr = hi ? g[4] : g[2]; gi = hi ? g[5] : g[3];
  } else {
    const bool ct = (lane & CM) != 0;
    float f0r = hi ? g[6]  : g[0],  f0i = hi ? g[7]  : g[1];
    float g0r = hi ? g[4]  : g[2],  g0i = hi ? g[5]  : g[3];
    float f1r = hi ? g[14] : g[8],  f1i = hi ? g[15] : g[9];
    float g1r = hi ? g[12] : g[10], g1i = hi ? g[13] : g[11];
    fr = ct ? f1r : f0r; fi = ct ? f1i : f0i;
    gr = ct ? g1r : g0r; gi = ct ? g1i : g0i;
  }
  v2f vfr = sp(fr), vfi = sp(fi), vgr = sp(gr), vgi = sp(gi);
  v2f vfiN = sp(-fi), vgiN = sp(-gi);
#pragma unroll
  for (int r = 0; r < 16; ++r) {
    v2f pR = bfly2<M>(Sr[r]);
    v2f pI = bfly2<M>(Si[r]);
    v2f nR = vfma(vgiN, pI, vfma(vgr, pR, vfma(vfiN, Si[r], vfr * Sr[r])));
    v2f nI = vfma(vgi,  pR, vfma(vgr, pI, vfma(vfi,  Sr[r], vfr * Si[r])));
    Sr[r] = nR; Si[r] = nI;
  }
}

__device__ __forceinline__ void mixP(v2f& x0r, v2f& x0i, v2f& x1r, v2f& x1i,
    float m0r, float m0i, float m1r, float m1i,
    float m2r, float m2i, float m3r, float m3i) {
  v2f n0r = vfma(sp(-m1i), x1i, vfma(sp(m1r), x1r, vfma(sp(-m0i), x0i, sp(m0r) * x0r)));
  v2f n0i = vfma(sp( m1i), x1r, vfma(sp(m1r), x1i, vfma(sp( m0i), x0r, sp(m0r) * x0i)));
  v2f n1r = vfma(sp(-m3i), x1i, vfma(sp(m3r), x1r, vfma(sp(-m2i), x0i, sp(m2r) * x0r)));
  v2f n1i = vfma(sp( m3i), x1r, vfma(sp(m3r), x1i, vfma(sp( m2i), x0r, sp(m2r) * x0i)));
  x0r = n0r; x0i = n0i; x1r = n1r; x1i = n1i;
}

// F4: fused u3(w4)+cu3(3->4): ctrl lane bit0 (wire 3), target r bit3.
__device__ __forceinline__ void f4N(v2f Sr[16], v2f Si[16],
    const float* __restrict__ g, int lane) {
  const bool ct = (lane & 1) != 0;
  float m[8];
#pragma unroll
  for (int jj = 0; jj < 8; ++jj) m[jj] = ct ? g[8 + jj] : g[jj];
#pragma unroll
  for (int r = 0; r < 8; ++r)
    mixP(Sr[r], Si[r], Sr[r + 8], Si[r + 8],
         m[0], m[1], m[2], m[3], m[4], m[5], m[6], m[7]);
}
// F5: ctrl r bit3, target r bit2.
__device__ __forceinline__ void f5N(v2f Sr[16], v2f Si[16],
    const float* __restrict__ g) {
#pragma unroll
  for (int r = 0; r < 4; ++r)
    mixP(Sr[r], Si[r], Sr[r + 4], Si[r + 4],
         g[0], g[1], g[2], g[3], g[4], g[5], g[6], g[7]);
#pragma unroll
  for (int r = 8; r < 12; ++r)
    mixP(Sr[r], Si[r], Sr[r + 4], Si[r + 4],
         g[8], g[9], g[10], g[11], g[12], g[13], g[14], g[15]);
}
// F6: ctrl r bit2, target r bit1.
__device__ __forceinline__ void f6N(v2f Sr[16], v2f Si[16],
    const float* __restrict__ g) {
#pragma unroll
  for (int t = 0; t < 4; ++t) {
    const int r0 = (t >> 1) * 8 + (t & 1);
    mixP(Sr[r0], Si[r0], Sr[r0 + 2], Si[r0 + 2],
         g[0], g[1], g[2], g[3], g[4], g[5], g[6], g[7]);
    const int r1 = r0 + 4;
    mixP(Sr[r1], Si[r1], Sr[r1 + 2], Si[r1 + 2],
         g[8], g[9], g[10], g[11], g[12], g[13], g[14], g[15]);
  }
}
// F7: ctrl r bit1, target r bit0.
__device__ __forceinline__ void f7N(v2f Sr[16], v2f Si[16],
    const float* __restrict__ g) {
#pragma unroll
  for (int t = 0; t < 4; ++t) {
    const int r0 = t * 4;
    mixP(Sr[r0], Si[r0], Sr[r0 + 1], Si[r0 + 1],
         g[0], g[1], g[2], g[3], g[4], g[5], g[6], g[7]);
    const int r1 = r0 + 2;
    mixP(Sr[r1], Si[r1], Sr[r1 + 1], Si[r1 + 1],
         g[8], g[9], g[10], g[11], g[12], g[13], g[14], g[15]);
  }
}
// F8': fused cu3(7->0)+next u3(w0): ctrl r bit0, target mask 8.
__device__ __forceinline__ void f8pN(v2f Sr[16], v2f Si[16],
    const float* __restrict__ g, int lane) {
  const bool hi = (lane & 8) != 0;
  float fr[2], fi[2], gr[2], gi[2];
  fr[0] = hi ? g[6]  : g[0];  fi[0] = hi ? g[7]  : g[1];
  gr[0] = hi ? g[4]  : g[2];  gi[0] = hi ? g[5]  : g[3];
  fr[1] = hi ? g[14] : g[8];  fi[1] = hi ? g[15] : g[9];
  gr[1] = hi ? g[12] : g[10]; gi[1] = hi ? g[13] : g[11];
#pragma unroll
  for (int r = 0; r < 16; ++r) {
    const int m = r & 1;
    v2f pR = bfly2<8>(Sr[r]);
    v2f pI = bfly2<8>(Si[r]);
    v2f nR = vfma(sp(-gi[m]), pI, vfma(sp(gr[m]), pR, vfma(sp(-fi[m]), Si[r], sp(fr[m]) * Sr[r])));
    v2f nI = vfma(sp( gi[m]), pR, vfma(sp(gr[m]), pI, vfma(sp( fi[m]), Sr[r], sp(fr[m]) * Si[r])));
    Sr[r] = nR; Si[r] = nI;
  }
}
// F8 final standalone cu3(7->0): odd r only, target mask 8.
__device__ __forceinline__ void f8N(v2f Sr[16], v2f Si[16],
    const float* __restrict__ g, int lane) {
  const bool hi = (lane & 8) != 0;
  const float fr = hi ? g[6] : g[0], fi = hi ? g[7] : g[1];
  const float gr = hi ? g[4] : g[2], gi = hi ? g[5] : g[3];
#pragma unroll
  for (int r = 1; r < 16; r += 2) {
    v2f pR = bfly2<8>(Sr[r]);
    v2f pI = bfly2<8>(Si[r]);
    v2f nR = vfma(sp(-gi), pI, vfma(sp(gr), pR, vfma(sp(-fi), Si[r], sp(fr) * Sr[r])));
    v2f nI = vfma(sp( gi), pR, vfma(sp(gr), pI, vfma(sp( fi), Sr[r], sp(fr) * Si[r])));
    Sr[r] = nR; Si[r] = nI;
  }
}

// Off-diagonal pair sum for a cross wire (mask M): per-lane partials.
template<int M>
__device__ __forceinline__ void crossO(const v2f Sr[16], const v2f Si[16],
                                       v2f& re, v2f& im) {
  v2f r = sp(0.0f), i = sp(0.0f);
#pragma unroll
  for (int k = 0; k < 16; ++k) {
    v2f pr = bfly2<M>(Sr[k]);
    v2f pi = bfly2<M>(Si[k]);
    r = vfma(Sr[k], pr, r);
    r = vfma(Si[k], pi, r);
    i = vfma(Si[k], pr, i);
    i = vfma(-Sr[k], pi, i);
  }
  re = r; im = i;
}

// ---------------------------------------------------------------------------
// Prep: G table unchanged. FCW3[c*24+t] = fcw * (2 if stage>=1 && wire>=4
// else 1) — intra pairs counted once (need mx=2Re, my=2Im); cross pairs
// counted twice by the group sum.
// ---------------------------------------------------------------------------
__device__ __forceinline__ void mm2(const float* A, const float* B, float* D) {
  D[0] = A[0]*B[0] - A[1]*B[1] + A[2]*B[4] - A[3]*B[5];
  D[1] = A[0]*B[1] + A[1]*B[0] + A[2]*B[5] + A[3]*B[4];
  D[2] = A[0]*B[2] - A[1]*B[3] + A[2]*B[6] - A[3]*B[7];
  D[3] = A[0]*B[3] + A[1]*B[2] + A[2]*B[7] + A[3]*B[6];
  D[4] = A[4]*B[0] - A[5]*B[1] + A[6]*B[4] - A[7]*B[5];
  D[5] = A[4]*B[1] + A[5]*B[0] + A[6]*B[5] + A[7]*B[4];
  D[6] = A[4]*B[2] - A[5]*B[3] + A[6]*B[6] - A[7]*B[7];
  D[7] = A[4]*B[3] + A[5]*B[2] + A[6]*B[7] + A[7]*B[6];
}
__device__ __forceinline__ void u3fill(const float* src, float* o) {
  float th = src[0], ph = src[1], lam = src[2];
  float c = cosf(0.5f * th), s = sinf(0.5f * th);
  float cl = cosf(lam), sl = sinf(lam);
  float cp = cosf(ph), spv = sinf(ph);
  float cpl = cosf(ph + lam), spl = sinf(ph + lam);
  o[0] = c;        o[1] = 0.0f;
  o[2] = -cl * s;  o[3] = -sl * s;
  o[4] = cp * s;   o[5] = spv * s;
  o[6] = cpl * c;  o[7] = spl * c;
}

__global__ __launch_bounds__(128) void prep_kernel(
    const float* __restrict__ u3p, const float* __restrict__ cu3p,
    const float* __restrict__ fcw, float* __restrict__ G,
    float* __restrict__ FCW3) {
  __shared__ float Us[40][8];
  __shared__ float Cs[40][8];
  int t = threadIdx.x;
  if (t < 40) u3fill(u3p + t * 3, Us[t]);
  if (t >= 64 && t < 104) u3fill(cu3p + (t - 64) * 3, Cs[t - 64]);
  __syncthreads();
  if (t == 0) {
#pragma unroll
    for (int j = 0; j < 8; ++j) G[j] = Us[0][j];
  } else if (t < 36) {
    int j = t - 1, b = j / 7, k = j % 7;
    float* dst = G + 8 + b * 112 + k * 16;
    const float* U = Us[b * 8 + k + 1];
    const float* C = Cs[b * 8 + k];
#pragma unroll
    for (int q = 0; q < 8; ++q) dst[q] = U[q];
    mm2(C, U, dst + 8);
  } else if (t < 40) {
    int b = t - 36;
    float* dst = G + 568 + b * 16;
    const float* U = Us[(b + 1) * 8];
    const float* C = Cs[b * 8 + 7];
#pragma unroll
    for (int q = 0; q < 8; ++q) dst[q] = U[q];
    mm2(U, C, dst + 8);
  } else if (t == 40) {
#pragma unroll
    for (int j = 0; j < 8; ++j) G[632 + j] = Cs[39][j];
  }
  for (int i = t; i < 768; i += 128) {
    int tt = i % 24;
    int stage = tt >> 3, w = tt & 7;
    float sc = (stage >= 1 && w >= 4) ? 2.0f : 1.0f;
    FCW3[i] = fcw[i] * sc;
  }
}

// ---------------------------------------------------------------------------
// Fused conv + qsim, 8 px/wave. Direct Pauli expectations (no H/Y passes);
// FIX vs round 9: group-reduce the 24 partials to uniform values FIRST
// (mask-8 v2f step, pixel select, masks 1/2/4 scalar), THEN the per-lane
// per-channel FC dot. Per-lane weights before reduction mixed channels.
// ---------------------------------------------------------------------------
__global__ __launch_bounds__(256) void qconv_kernel(
    const float* __restrict__ x, const float* __restrict__ cw,
    const float* __restrict__ cb, const float* __restrict__ G,
    const float* __restrict__ FCW3, const float* __restrict__ fcb,
    float* __restrict__ out) {
  const int lane = threadIdx.x & 63;
  const int wid = __builtin_amdgcn_readfirstlane(
      (int)((blockIdx.x * blockDim.x + threadIdx.x) >> 6));
  const int p0 = wid * 8;
  const int q = lane & 15;

  // ---- conv: lane = (px = lane>>3, oc = lane&7) ----
  float ang;
  {
    const int px = lane >> 3;
    const int oc = lane & 7;
    const int p  = p0 + px;
    const int b  = p >> 12;
    const int hh = (p >> 6) & 63;
    const int wim = p & 63;
    float acc = cb[oc];
#pragma unroll 4
    for (int ic = 0; ic < 16; ++ic) {
      const float* wp = cw + (oc * 16 + ic) * 9;
      const float* xp = x + (b * 16 + ic) * 4096;
#pragma unroll
      for (int kh = 0; kh < 3; ++kh) {
        int ih = hh + kh - 1;
        bool rok = (unsigned)ih < 64u;
        int ihc = rok ? ih : 0;
#pragma unroll
        for (int kw = 0; kw < 3; ++kw) {
          int iw = wim + kw - 1;
          bool ok = rok && ((unsigned)iw < 64u);
          int iwc = ((unsigned)iw < 64u) ? iw : 0;
          float xv = xp[ihc * 64 + iwc];
          acc = fmaf(ok ? xv : 0.0f, wp[kh * 3 + kw], acc);
        }
      }
    }
    ang = acc;
  }

  // ---- gather 16 angles, build product state with F0 folded ----
  v2f Sr[16], Si[16];
  {
    const int gb = (lane & 48) << 2;
    float aA[8], aB[8];
#pragma unroll
    for (int w = 0; w < 8; ++w) {
      aA[w] = bperm(ang, gb + (w << 2));
      aB[w] = bperm(ang, gb + ((8 + w) << 2));
    }
    float cA[8], sA[8], cB[8], sB[8];
#pragma unroll
    for (int w = 0; w < 8; ++w) {
      __sincosf(0.5f * aA[w], &sA[w], &cA[w]);
      __sincosf(0.5f * aB[w], &sB[w], &cB[w]);
    }
    v2f c0; c0.x = cA[0]; c0.y = cB[0];
    v2f s0; s0.x = sA[0]; s0.y = sB[0];
    v2f c0r = vfma(sp(G[2]), s0, sp(G[0]) * c0);
    v2f c0i = vfma(sp(G[3]), s0, sp(G[1]) * c0);
    v2f s0r = vfma(sp(G[6]), s0, sp(G[4]) * c0);
    v2f s0i = vfma(sp(G[7]), s0, sp(G[5]) * c0);
    const bool w0 = (q & 8) != 0;
    v2f selR = w0 ? s0r : c0r;
    v2f selI = w0 ? s0i : c0i;
    float fA = ((q & 4) ? sA[1] : cA[1]) * ((q & 2) ? sA[2] : cA[2])
             * ((q & 1) ? sA[3] : cA[3]);
    float fB = ((q & 4) ? sB[1] : cB[1]) * ((q & 2) ? sB[2] : cB[2])
             * ((q & 1) ? sB[3] : cB[3]);
    v2f uu[4], vv[4];
    uu[0].x = cA[6]*cA[7]; uu[1].x = cA[6]*sA[7];
    uu[2].x = sA[6]*cA[7]; uu[3].x = sA[6]*sA[7];
    uu[0].y = cB[6]*cB[7]; uu[1].y = cB[6]*sB[7];
    uu[2].y = sB[6]*cB[7]; uu[3].y = sB[6]*sB[7];
    float vA0 = fA * cA[4], vA1 = fA * sA[4];
    float vB0 = fB * cB[4], vB1 = fB * sB[4];
    vv[0].x = vA0*cA[5]; vv[1].x = vA0*sA[5];
    vv[2].x = vA1*cA[5]; vv[3].x = vA1*sA[5];
    vv[0].y = vB0*cB[5]; vv[1].y = vB0*sB[5];
    vv[2].y = vB1*cB[5]; vv[3].y = vB1*sB[5];
#pragma unroll
    for (int r = 0; r < 16; ++r) {
      v2f base = vv[r >> 2] * uu[r & 3];
      Sr[r] = selR * base;
      Si[r] = selI * base;
    }
  }

  // ---- fused circuit (F0 applied in init) ----
  for (int b = 0; b < 5; ++b) {
    const float* base = G + 8 + b * 112;
    crossG<4, 8>(Sr, Si, base +  0, lane);
    crossG<2, 4>(Sr, Si, base + 16, lane);
    crossG<1, 2>(Sr, Si, base + 32, lane);
    f4N(Sr, Si, base + 48, lane);
    f5N(Sr, Si, base + 64);
    f6N(Sr, Si, base + 80);
    f7N(Sr, Si, base + 96);
    if (b < 4) f8pN(Sr, Si, G + 568 + b * 16, lane);
  }
  f8N(Sr, Si, G + 632, lane);

  // ---- per-lane measurement partials ----
  float sg[4];
  sg[0] = (q & 8) ? -1.0f : 1.0f;
  sg[1] = (q & 4) ? -1.0f : 1.0f;
  sg[2] = (q & 2) ? -1.0f : 1.0f;
  sg[3] = (q & 1) ? -1.0f : 1.0f;

  v2f PT[24];
  {
    v2f re0, im0, re1, im1, re2, im2, re3, im3;
    crossO<8>(Sr, Si, re0, im0);
    crossO<4>(Sr, Si, re1, im1);
    crossO<2>(Sr, Si, re2, im2);
    crossO<1>(Sr, Si, re3, im3);
    PT[8]  = re0; PT[9]  = re1; PT[10] = re2; PT[11] = re3;
    PT[16] = sp(sg[0]) * im0; PT[17] = sp(sg[1]) * im1;
    PT[18] = sp(sg[2]) * im2; PT[19] = sp(sg[3]) * im3;

    v2f P[16];
#pragma unroll
    for (int r = 0; r < 16; ++r) P[r] = vfma(Si[r], Si[r], Sr[r] * Sr[r]);
    v2f t01[8];
#pragma unroll
    for (int k = 0; k < 8; ++k) t01[k] = P[2*k] + P[2*k+1];
    v2f q0 = t01[0] + t01[1], q1 = t01[2] + t01[3];
    v2f q2 = t01[4] + t01[5], q3 = t01[6] + t01[7];
    v2f h0 = q0 + q1, h1 = q2 + q3;
    v2f p  = h0 + h1;
    PT[4] = h0 - h1;
    PT[5] = (q0 - q1) + (q2 - q3);
    PT[6] = (t01[0]-t01[1]) + (t01[2]-t01[3])
          + (t01[4]-t01[5]) + (t01[6]-t01[7]);
    PT[7] = (P[0]-P[1]) + (P[2]-P[3]) + (P[4]-P[5]) + (P[6]-P[7])
          + (P[8]-P[9]) + (P[10]-P[11]) + (P[12]-P[13]) + (P[14]-P[15]);
    PT[0] = sp(sg[0]) * p; PT[1] = sp(sg[1]) * p;
    PT[2] = sp(sg[2]) * p; PT[3] = sp(sg[3]) * p;

    v2f re, im;
    re = sp(0.0f); im = sp(0.0f);
#pragma unroll
    for (int r = 0; r < 8; ++r) {
      re = vfma(Sr[r], Sr[r+8], re); re = vfma(Si[r], Si[r+8], re);
      im = vfma(Si[r], Sr[r+8], im); im = vfma(-Sr[r], Si[r+8], im);
    }
    PT[12] = re; PT[20] = im;
    re = sp(0.0f); im = sp(0.0f);
#pragma unroll
    for (int t = 0; t < 8; ++t) {
      const int lo = (t & 3) + (t >> 2) * 8;
      re = vfma(Sr[lo], Sr[lo+4], re); re = vfma(Si[lo], Si[lo+4], re);
      im = vfma(Si[lo], Sr[lo+4], im); im = vfma(-Sr[lo], Si[lo+4], im);
    }
    PT[13] = re; PT[21] = im;
    re = sp(0.0f); im = sp(0.0f);
#pragma unroll
    for (int t = 0; t < 8; ++t) {
      const int lo = (t & 1) + (t >> 1) * 4;
      re = vfma(Sr[lo], Sr[lo+2], re); re = vfma(Si[lo], Si[lo+2], re);
      im = vfma(Si[lo], Sr[lo+2], im); im = vfma(-Sr[lo], Si[lo+2], im);
    }
    PT[14] = re; PT[22] = im;
    re = sp(0.0f); im = sp(0.0f);
#pragma unroll
    for (int t = 0; t < 8; ++t) {
      const int lo = 2 * t;
      re = vfma(Sr[lo], Sr[lo+1], re); re = vfma(Si[lo], Si[lo+1], re);
      im = vfma(Si[lo], Sr[lo+1], im); im = vfma(-Sr[lo], Si[lo+1], im);
    }
    PT[15] = re; PT[23] = im;
  }

  // ---- group-reduce partials to uniform values, THEN per-channel FC ----
  const int j = q & 7;
  const bool isB = (q & 8) != 0;
  float mm[24];
#pragma unroll
  for (int t = 0; t < 24; ++t) {
    v2f v = PT[t] + bfly2<8>(PT[t]);   // pair over mask 8 (both pixels)
    float s = isB ? v.y : v.x;          // keep own pixel
    s += bfly<1>(s);
    s += bfly<2>(s);
    s += bfly<4>(s);                    // completes the 16-lane sum
    mm[t] = s;
  }

  const int g = lane >> 4;
  const int p = p0 + 2 * g + (isB ? 1 : 0);
  const int ob = (p >> 12) * 131072 + (p & 4095);
#pragma unroll
  for (int k = 0; k < 4; ++k) {
    const int ch = 4 * j + k;
    const float4* w4 = reinterpret_cast<const float4*>(FCW3 + ch * 24);
    float acc = fcb[ch];
#pragma unroll
    for (int u = 0; u < 6; ++u) {
      float4 tv = w4[u];
      acc = fmaf(mm[u*4+0], tv.x, acc);
      acc = fmaf(mm[u*4+1], tv.y, acc);
      acc = fmaf(mm[u*4+2], tv.z, acc);
      acc = fmaf(mm[u*4+3], tv.w, acc);
    }
    out[ob + ch * 4096] = acc;
  }
}

extern "C" void kernel_launch(void* const* d_in, const int* in_sizes, int n_in,
                              void* d_out, int out_size, void* d_ws, size_t ws_size,
                              hipStream_t stream) {
  const float* x      = (const float*)d_in[0];
  const float* conv_w = (const float*)d_in[1];
  const float* conv_b = (const float*)d_in[2];
  const float* u3p    = (const float*)d_in[3];
  const float* cu3p   = (const float*)d_in[4];
  const float* fcw    = (const float*)d_in[5];
  const float* fcb    = (const float*)d_in[6];
  float* out = (float*)d_out;

  float* ws   = (float*)d_ws;
  float* G    = ws;          // 640 (fused gate matrices)
  float* FCW3 = ws + 640;    // 768 (channel-major, intra x/y wires x2)

  prep_kernel<<<1, 128, 0, stream>>>(u3p, cu3p, fcw, G, FCW3);
  qconv_kernel<<<512, 256, 0, stream>>>(x, conv_w, conv_b, G, FCW3, fcb, out);
}

// Round 11
// 106.999 us; speedup vs baseline: 1.1133x; 1.0698x over previous
//
#include <hip/hip_runtime.h>

typedef float v2f __attribute__((ext_vector_type(2)));

// ---------------------------------------------------------------------------
// Cross-lane helpers: masks 1,2,8 via DPP (VALU pipe), mask 4 via ds_swizzle;
// ds_bpermute only for the one-time angle gather.
// ---------------------------------------------------------------------------
template<int C>
__device__ __forceinline__ float dppmov(float x) {
  return __int_as_float(__builtin_amdgcn_update_dpp(0, __float_as_int(x), C, 0xF, 0xF, true));
}
template<int IMM>
__device__ __forceinline__ float dswz(float x) {
  return __int_as_float(__builtin_amdgcn_ds_swizzle(__float_as_int(x), IMM));
}
__device__ __forceinline__ float bperm(float x, int a) {
  return __int_as_float(__builtin_amdgcn_ds_bpermute(a, __float_as_int(x)));
}
template<int M>
__device__ __forceinline__ float bfly(float x) {
  if constexpr (M == 1)      return dppmov<0xB1>(x);   // quad_perm [1,0,3,2]
  else if constexpr (M == 2) return dppmov<0x4E>(x);   // quad_perm [2,3,0,1]
  else if constexpr (M == 8) return dppmov<0x128>(x);  // row_ror:8 == xor8
  else                       return dswz<0x101F>(x);   // M==4: bit-mode xor4
}
template<int M>
__device__ __forceinline__ v2f bfly2(v2f v) {
  v2f o; o.x = bfly<M>(v.x); o.y = bfly<M>(v.y); return o;
}
__device__ __forceinline__ v2f sp(float s) { v2f v; v.x = s; v.y = s; return v; }
__device__ __forceinline__ v2f vfma(v2f a, v2f b, v2f c) {
  return __builtin_elementwise_fma(a, b, c);
}

// ---------------------------------------------------------------------------
// Layout: 8 pixels/wave. Group g = lane>>4 holds the packed pixel pair in v2f.
// Amp i = q*16 + r, q = lane&15, r = 0..15. Wires 0..3 <-> q bits 3..0
// (masks 8,4,2,1); wires 4..7 <-> r bits 3..0.
// ---------------------------------------------------------------------------
template<int M, int CM>
__device__ __forceinline__ void crossG(v2f Sr[16], v2f Si[16],
    const float* g, int lane) {
  const bool hi = (lane & M) != 0;
  float fr, fi, gr, gi;
  if constexpr (CM == 0) {
    fr = hi ? g[6] : g[0]; fi = hi ? g[7] : g[1];
    gr = hi ? g[4] : g[2]; gi = hi ? g[5] : g[3];
  } else {
    const bool ct = (lane & CM) != 0;
    float f0r = hi ? g[6]  : g[0],  f0i = hi ? g[7]  : g[1];
    float g0r = hi ? g[4]  : g[2],  g0i = hi ? g[5]  : g[3];
    float f1r = hi ? g[14] : g[8],  f1i = hi ? g[15] : g[9];
    float g1r = hi ? g[12] : g[10], g1i = hi ? g[13] : g[11];
    fr = ct ? f1r : f0r; fi = ct ? f1i : f0i;
    gr = ct ? g1r : g0r; gi = ct ? g1i : g0i;
  }
  v2f vfr = sp(fr), vfi = sp(fi), vgr = sp(gr), vgi = sp(gi);
  v2f vfiN = sp(-fi), vgiN = sp(-gi);
#pragma unroll
  for (int r = 0; r < 16; ++r) {
    v2f pR = bfly2<M>(Sr[r]);
    v2f pI = bfly2<M>(Si[r]);
    v2f nR = vfma(vgiN, pI, vfma(vgr, pR, vfma(vfiN, Si[r], vfr * Sr[r])));
    v2f nI = vfma(vgi,  pR, vfma(vgr, pI, vfma(vfi,  Sr[r], vfr * Si[r])));
    Sr[r] = nR; Si[r] = nI;
  }
}

__device__ __forceinline__ void mixP(v2f& x0r, v2f& x0i, v2f& x1r, v2f& x1i,
    float m0r, float m0i, float m1r, float m1i,
    float m2r, float m2i, float m3r, float m3i) {
  v2f n0r = vfma(sp(-m1i), x1i, vfma(sp(m1r), x1r, vfma(sp(-m0i), x0i, sp(m0r) * x0r)));
  v2f n0i = vfma(sp( m1i), x1r, vfma(sp(m1r), x1i, vfma(sp( m0i), x0r, sp(m0r) * x0i)));
  v2f n1r = vfma(sp(-m3i), x1i, vfma(sp(m3r), x1r, vfma(sp(-m2i), x0i, sp(m2r) * x0r)));
  v2f n1i = vfma(sp( m3i), x1r, vfma(sp(m3r), x1i, vfma(sp( m2i), x0r, sp(m2r) * x0i)));
  x0r = n0r; x0i = n0i; x1r = n1r; x1i = n1i;
}

// F4: fused u3(w4)+cu3(3->4): ctrl lane bit0 (wire 3), target r bit3.
__device__ __forceinline__ void f4N(v2f Sr[16], v2f Si[16],
    const float* g, int lane) {
  const bool ct = (lane & 1) != 0;
  float m[8];
#pragma unroll
  for (int jj = 0; jj < 8; ++jj) m[jj] = ct ? g[8 + jj] : g[jj];
#pragma unroll
  for (int r = 0; r < 8; ++r)
    mixP(Sr[r], Si[r], Sr[r + 8], Si[r + 8],
         m[0], m[1], m[2], m[3], m[4], m[5], m[6], m[7]);
}
// F5: ctrl r bit3, target r bit2.
__device__ __forceinline__ void f5N(v2f Sr[16], v2f Si[16], const float* g) {
#pragma unroll
  for (int r = 0; r < 4; ++r)
    mixP(Sr[r], Si[r], Sr[r + 4], Si[r + 4],
         g[0], g[1], g[2], g[3], g[4], g[5], g[6], g[7]);
#pragma unroll
  for (int r = 8; r < 12; ++r)
    mixP(Sr[r], Si[r], Sr[r + 4], Si[r + 4],
         g[8], g[9], g[10], g[11], g[12], g[13], g[14], g[15]);
}
// F6: ctrl r bit2, target r bit1.
__device__ __forceinline__ void f6N(v2f Sr[16], v2f Si[16], const float* g) {
#pragma unroll
  for (int t = 0; t < 4; ++t) {
    const int r0 = (t >> 1) * 8 + (t & 1);
    mixP(Sr[r0], Si[r0], Sr[r0 + 2], Si[r0 + 2],
         g[0], g[1], g[2], g[3], g[4], g[5], g[6], g[7]);
    const int r1 = r0 + 4;
    mixP(Sr[r1], Si[r1], Sr[r1 + 2], Si[r1 + 2],
         g[8], g[9], g[10], g[11], g[12], g[13], g[14], g[15]);
  }
}
// F7: ctrl r bit1, target r bit0.
__device__ __forceinline__ void f7N(v2f Sr[16], v2f Si[16], const float* g) {
#pragma unroll
  for (int t = 0; t < 4; ++t) {
    const int r0 = t * 4;
    mixP(Sr[r0], Si[r0], Sr[r0 + 1], Si[r0 + 1],
         g[0], g[1], g[2], g[3], g[4], g[5], g[6], g[7]);
    const int r1 = r0 + 2;
    mixP(Sr[r1], Si[r1], Sr[r1 + 1], Si[r1 + 1],
         g[8], g[9], g[10], g[11], g[12], g[13], g[14], g[15]);
  }
}
// F8': fused cu3(7->0)+next u3(w0): ctrl r bit0, target mask 8.
__device__ __forceinline__ void f8pN(v2f Sr[16], v2f Si[16],
    const float* g, int lane) {
  const bool hi = (lane & 8) != 0;
  float fr[2], fi[2], gr[2], gi[2];
  fr[0] = hi ? g[6]  : g[0];  fi[0] = hi ? g[7]  : g[1];
  gr[0] = hi ? g[4]  : g[2];  gi[0] = hi ? g[5]  : g[3];
  fr[1] = hi ? g[14] : g[8];  fi[1] = hi ? g[15] : g[9];
  gr[1] = hi ? g[12] : g[10]; gi[1] = hi ? g[13] : g[11];
#pragma unroll
  for (int r = 0; r < 16; ++r) {
    const int m = r & 1;
    v2f pR = bfly2<8>(Sr[r]);
    v2f pI = bfly2<8>(Si[r]);
    v2f nR = vfma(sp(-gi[m]), pI, vfma(sp(gr[m]), pR, vfma(sp(-fi[m]), Si[r], sp(fr[m]) * Sr[r])));
    v2f nI = vfma(sp( gi[m]), pR, vfma(sp(gr[m]), pI, vfma(sp( fi[m]), Sr[r], sp(fr[m]) * Si[r])));
    Sr[r] = nR; Si[r] = nI;
  }
}
// F8 final standalone cu3(7->0): odd r only, target mask 8.
__device__ __forceinline__ void f8N(v2f Sr[16], v2f Si[16],
    const float* g, int lane) {
  const bool hi = (lane & 8) != 0;
  const float fr = hi ? g[6] : g[0], fi = hi ? g[7] : g[1];
  const float gr = hi ? g[4] : g[2], gi = hi ? g[5] : g[3];
#pragma unroll
  for (int r = 1; r < 16; r += 2) {
    v2f pR = bfly2<8>(Sr[r]);
    v2f pI = bfly2<8>(Si[r]);
    v2f nR = vfma(sp(-gi), pI, vfma(sp(gr), pR, vfma(sp(-fi), Si[r], sp(fr) * Sr[r])));
    v2f nI = vfma(sp( gi), pR, vfma(sp(gr), pI, vfma(sp( fi), Sr[r], sp(fr) * Si[r])));
    Sr[r] = nR; Si[r] = nI;
  }
}

// Off-diagonal pair sum for a cross wire (mask M): per-lane partials.
template<int M>
__device__ __forceinline__ void crossO(const v2f Sr[16], const v2f Si[16],
                                       v2f& re, v2f& im) {
  v2f r = sp(0.0f), i = sp(0.0f);
#pragma unroll
  for (int k = 0; k < 16; ++k) {
    v2f pr = bfly2<M>(Sr[k]);
    v2f pi = bfly2<M>(Si[k]);
    r = vfma(Sr[k], pr, r);
    r = vfma(Si[k], pi, r);
    i = vfma(Si[k], pr, i);
    i = vfma(-Sr[k], pi, i);
  }
  re = r; im = i;
}

// ---------------------------------------------------------------------------
// Prep helpers (complex 2x2 product; u3 matrix fill).
// ---------------------------------------------------------------------------
__device__ __forceinline__ void mm2(const float* A, const float* B, float* D) {
  D[0] = A[0]*B[0] - A[1]*B[1] + A[2]*B[4] - A[3]*B[5];
  D[1] = A[0]*B[1] + A[1]*B[0] + A[2]*B[5] + A[3]*B[4];
  D[2] = A[0]*B[2] - A[1]*B[3] + A[2]*B[6] - A[3]*B[7];
  D[3] = A[0]*B[3] + A[1]*B[2] + A[2]*B[7] + A[3]*B[6];
  D[4] = A[4]*B[0] - A[5]*B[1] + A[6]*B[4] - A[7]*B[5];
  D[5] = A[4]*B[1] + A[5]*B[0] + A[6]*B[5] + A[7]*B[4];
  D[6] = A[4]*B[2] - A[5]*B[3] + A[6]*B[6] - A[7]*B[7];
  D[7] = A[4]*B[3] + A[5]*B[2] + A[6]*B[7] + A[7]*B[6];
}
__device__ __forceinline__ void u3fill(const float* src, float* o) {
  float th = src[0], ph = src[1], lam = src[2];
  float c = cosf(0.5f * th), s = sinf(0.5f * th);
  float cl = cosf(lam), sl = sinf(lam);
  float cp = cosf(ph), spv = sinf(ph);
  float cpl = cosf(ph + lam), spl = sinf(ph + lam);
  o[0] = c;        o[1] = 0.0f;
  o[2] = -cl * s;  o[3] = -sl * s;
  o[4] = cp * s;   o[5] = spv * s;
  o[6] = cpl * c;  o[7] = spl * c;
}

// ---------------------------------------------------------------------------
// Single fused kernel: per-block in-LDS prep (G table + scaled FC weights),
// then conv + qsim + direct-Pauli measurement + FC. One dispatch total —
// removes the prep launch + dependency and turns gate-coefficient fetches
// into pipelined LDS reads (SGPR budget of 64 forced serial scalar reloads).
// ---------------------------------------------------------------------------
__global__ __launch_bounds__(256) void qconv_kernel(
    const float* __restrict__ x, const float* __restrict__ cw,
    const float* __restrict__ cb, const float* __restrict__ u3p,
    const float* __restrict__ cu3p, const float* __restrict__ fcw,
    const float* __restrict__ fcb, float* __restrict__ out) {
  __shared__ float Us[40][8];
  __shared__ float Cs[40][8];
  __shared__ float Gs[640];
  __shared__ float FCWs[768];

  // ---- in-block prep (identical algebra to the round-3..10 prep kernel) ----
  {
    const int t = threadIdx.x;
    if (t < 40) u3fill(u3p + t * 3, Us[t]);
    if (t >= 64 && t < 104) u3fill(cu3p + (t - 64) * 3, Cs[t - 64]);
    __syncthreads();
    if (t == 0) {
#pragma unroll
      for (int j = 0; j < 8; ++j) Gs[j] = Us[0][j];
    } else if (t < 36) {
      int j = t - 1, b = j / 7, k = j % 7;
      float* dst = Gs + 8 + b * 112 + k * 16;
      const float* U = Us[b * 8 + k + 1];
      const float* C = Cs[b * 8 + k];
#pragma unroll
      for (int u = 0; u < 8; ++u) dst[u] = U[u];
      mm2(C, U, dst + 8);
    } else if (t < 40) {
      int b = t - 36;
      float* dst = Gs + 568 + b * 16;
      const float* U = Us[(b + 1) * 8];
      const float* C = Cs[b * 8 + 7];
#pragma unroll
      for (int u = 0; u < 8; ++u) dst[u] = U[u];
      mm2(U, C, dst + 8);
    } else if (t == 40) {
#pragma unroll
      for (int j = 0; j < 8; ++j) Gs[632 + j] = Cs[39][j];
    }
    // FC weights: x2 on intra wires (>=4) of stages x,y (intra pairs counted
    // once; cross pairs counted twice by the group sum).
    for (int i = t; i < 768; i += 256) {
      int tt = i % 24;
      int stage = tt >> 3, w = tt & 7;
      float sc = (stage >= 1 && w >= 4) ? 2.0f : 1.0f;
      FCWs[i] = fcw[i] * sc;
    }
    __syncthreads();
  }

  const int lane = threadIdx.x & 63;
  const int wid = __builtin_amdgcn_readfirstlane(
      (int)((blockIdx.x * blockDim.x + threadIdx.x) >> 6));
  const int p0 = wid * 8;
  const int q = lane & 15;

  // ---- conv: lane = (px = lane>>3, oc = lane&7) ----
  float ang;
  {
    const int px = lane >> 3;
    const int oc = lane & 7;
    const int p  = p0 + px;
    const int b  = p >> 12;
    const int hh = (p >> 6) & 63;
    const int wim = p & 63;
    float acc = cb[oc];
#pragma unroll 4
    for (int ic = 0; ic < 16; ++ic) {
      const float* wp = cw + (oc * 16 + ic) * 9;
      const float* xp = x + (b * 16 + ic) * 4096;
#pragma unroll
      for (int kh = 0; kh < 3; ++kh) {
        int ih = hh + kh - 1;
        bool rok = (unsigned)ih < 64u;
        int ihc = rok ? ih : 0;
#pragma unroll
        for (int kw = 0; kw < 3; ++kw) {
          int iw = wim + kw - 1;
          bool ok = rok && ((unsigned)iw < 64u);
          int iwc = ((unsigned)iw < 64u) ? iw : 0;
          float xv = xp[ihc * 64 + iwc];
          acc = fmaf(ok ? xv : 0.0f, wp[kh * 3 + kw], acc);
        }
      }
    }
    ang = acc;
  }

  // ---- gather 16 angles, build product state with F0 folded ----
  v2f Sr[16], Si[16];
  {
    const int gb = (lane & 48) << 2;
    float aA[8], aB[8];
#pragma unroll
    for (int w = 0; w < 8; ++w) {
      aA[w] = bperm(ang, gb + (w << 2));
      aB[w] = bperm(ang, gb + ((8 + w) << 2));
    }
    float cA[8], sA[8], cB[8], sB[8];
#pragma unroll
    for (int w = 0; w < 8; ++w) {
      __sincosf(0.5f * aA[w], &sA[w], &cA[w]);
      __sincosf(0.5f * aB[w], &sB[w], &cB[w]);
    }
    v2f c0; c0.x = cA[0]; c0.y = cB[0];
    v2f s0; s0.x = sA[0]; s0.y = sB[0];
    v2f c0r = vfma(sp(Gs[2]), s0, sp(Gs[0]) * c0);
    v2f c0i = vfma(sp(Gs[3]), s0, sp(Gs[1]) * c0);
    v2f s0r = vfma(sp(Gs[6]), s0, sp(Gs[4]) * c0);
    v2f s0i = vfma(sp(Gs[7]), s0, sp(Gs[5]) * c0);
    const bool w0 = (q & 8) != 0;
    v2f selR = w0 ? s0r : c0r;
    v2f selI = w0 ? s0i : c0i;
    float fA = ((q & 4) ? sA[1] : cA[1]) * ((q & 2) ? sA[2] : cA[2])
             * ((q & 1) ? sA[3] : cA[3]);
    float fB = ((q & 4) ? sB[1] : cB[1]) * ((q & 2) ? sB[2] : cB[2])
             * ((q & 1) ? sB[3] : cB[3]);
    v2f uu[4], vv[4];
    uu[0].x = cA[6]*cA[7]; uu[1].x = cA[6]*sA[7];
    uu[2].x = sA[6]*cA[7]; uu[3].x = sA[6]*sA[7];
    uu[0].y = cB[6]*cB[7]; uu[1].y = cB[6]*sB[7];
    uu[2].y = sB[6]*cB[7]; uu[3].y = sB[6]*sB[7];
    float vA0 = fA * cA[4], vA1 = fA * sA[4];
    float vB0 = fB * cB[4], vB1 = fB * sB[4];
    vv[0].x = vA0*cA[5]; vv[1].x = vA0*sA[5];
    vv[2].x = vA1*cA[5]; vv[3].x = vA1*sA[5];
    vv[0].y = vB0*cB[5]; vv[1].y = vB0*sB[5];
    vv[2].y = vB1*cB[5]; vv[3].y = vB1*sB[5];
#pragma unroll
    for (int r = 0; r < 16; ++r) {
      v2f base = vv[r >> 2] * uu[r & 3];
      Sr[r] = selR * base;
      Si[r] = selI * base;
    }
  }

  // ---- fused circuit (F0 applied in init) ----
  for (int b = 0; b < 5; ++b) {
    const float* base = Gs + 8 + b * 112;
    crossG<4, 8>(Sr, Si, base +  0, lane);
    crossG<2, 4>(Sr, Si, base + 16, lane);
    crossG<1, 2>(Sr, Si, base + 32, lane);
    f4N(Sr, Si, base + 48, lane);
    f5N(Sr, Si, base + 64);
    f6N(Sr, Si, base + 80);
    f7N(Sr, Si, base + 96);
    if (b < 4) f8pN(Sr, Si, Gs + 568 + b * 16, lane);
  }
  f8N(Sr, Si, Gs + 632, lane);

  // ---- per-lane measurement partials ----
  float sg[4];
  sg[0] = (q & 8) ? -1.0f : 1.0f;
  sg[1] = (q & 4) ? -1.0f : 1.0f;
  sg[2] = (q & 2) ? -1.0f : 1.0f;
  sg[3] = (q & 1) ? -1.0f : 1.0f;

  v2f PT[24];
  {
    v2f re0, im0, re1, im1, re2, im2, re3, im3;
    crossO<8>(Sr, Si, re0, im0);
    crossO<4>(Sr, Si, re1, im1);
    crossO<2>(Sr, Si, re2, im2);
    crossO<1>(Sr, Si, re3, im3);
    PT[8]  = re0; PT[9]  = re1; PT[10] = re2; PT[11] = re3;
    PT[16] = sp(sg[0]) * im0; PT[17] = sp(sg[1]) * im1;
    PT[18] = sp(sg[2]) * im2; PT[19] = sp(sg[3]) * im3;

    v2f P[16];
#pragma unroll
    for (int r = 0; r < 16; ++r) P[r] = vfma(Si[r], Si[r], Sr[r] * Sr[r]);
    v2f t01[8];
#pragma unroll
    for (int k = 0; k < 8; ++k) t01[k] = P[2*k] + P[2*k+1];
    v2f q0 = t01[0] + t01[1], q1 = t01[2] + t01[3];
    v2f q2 = t01[4] + t01[5], q3 = t01[6] + t01[7];
    v2f h0 = q0 + q1, h1 = q2 + q3;
    v2f p  = h0 + h1;
    PT[4] = h0 - h1;
    PT[5] = (q0 - q1) + (q2 - q3);
    PT[6] = (t01[0]-t01[1]) + (t01[2]-t01[3])
          + (t01[4]-t01[5]) + (t01[6]-t01[7]);
    PT[7] = (P[0]-P[1]) + (P[2]-P[3]) + (P[4]-P[5]) + (P[6]-P[7])
          + (P[8]-P[9]) + (P[10]-P[11]) + (P[12]-P[13]) + (P[14]-P[15]);
    PT[0] = sp(sg[0]) * p; PT[1] = sp(sg[1]) * p;
    PT[2] = sp(sg[2]) * p; PT[3] = sp(sg[3]) * p;

    v2f re, im;
    re = sp(0.0f); im = sp(0.0f);
#pragma unroll
    for (int r = 0; r < 8; ++r) {
      re = vfma(Sr[r], Sr[r+8], re); re = vfma(Si[r], Si[r+8], re);
      im = vfma(Si[r], Sr[r+8], im); im = vfma(-Sr[r], Si[r+8], im);
    }
    PT[12] = re; PT[20] = im;
    re = sp(0.0f); im = sp(0.0f);
#pragma unroll
    for (int t = 0; t < 8; ++t) {
      const int lo = (t & 3) + (t >> 2) * 8;
      re = vfma(Sr[lo], Sr[lo+4], re); re = vfma(Si[lo], Si[lo+4], re);
      im = vfma(Si[lo], Sr[lo+4], im); im = vfma(-Sr[lo], Si[lo+4], im);
    }
    PT[13] = re; PT[21] = im;
    re = sp(0.0f); im = sp(0.0f);
#pragma unroll
    for (int t = 0; t < 8; ++t) {
      const int lo = (t & 1) + (t >> 1) * 4;
      re = vfma(Sr[lo], Sr[lo+2], re); re = vfma(Si[lo], Si[lo+2], re);
      im = vfma(Si[lo], Sr[lo+2], im); im = vfma(-Sr[lo], Si[lo+2], im);
    }
    PT[14] = re; PT[22] = im;
    re = sp(0.0f); im = sp(0.0f);
#pragma unroll
    for (int t = 0; t < 8; ++t) {
      const int lo = 2 * t;
      re = vfma(Sr[lo], Sr[lo+1], re); re = vfma(Si[lo], Si[lo+1], re);
      im = vfma(Si[lo], Sr[lo+1], im); im = vfma(-Sr[lo], Si[lo+1], im);
    }
    PT[15] = re; PT[23] = im;
  }

  // ---- group-reduce partials to uniform values, THEN per-channel FC ----
  const int j = q & 7;
  const bool isB = (q & 8) != 0;
  float mm[24];
#pragma unroll
  for (int t = 0; t < 24; ++t) {
    v2f v = PT[t] + bfly2<8>(PT[t]);   // pair over mask 8 (both pixels)
    float s = isB ? v.y : v.x;          // keep own pixel
    s += bfly<1>(s);
    s += bfly<2>(s);
    s += bfly<4>(s);                    // completes the 16-lane sum
    mm[t] = s;
  }

  const int g = lane >> 4;
  const int p = p0 + 2 * g + (isB ? 1 : 0);
  const int ob = (p >> 12) * 131072 + (p & 4095);
#pragma unroll
  for (int k = 0; k < 4; ++k) {
    const int ch = 4 * j + k;
    const float* wr = FCWs + ch * 24;
    float acc = fcb[ch];
#pragma unroll
    for (int u = 0; u < 24; ++u) acc = fmaf(mm[u], wr[u], acc);
    out[ob + ch * 4096] = acc;
  }
}

extern "C" void kernel_launch(void* const* d_in, const int* in_sizes, int n_in,
                              void* d_out, int out_size, void* d_ws, size_t ws_size,
                              hipStream_t stream) {
  const float* x      = (const float*)d_in[0];
  const float* conv_w = (const float*)d_in[1];
  const float* conv_b = (const float*)d_in[2];
  const float* u3p    = (const float*)d_in[3];
  const float* cu3p   = (const float*)d_in[4];
  const float* fcw    = (const float*)d_in[5];
  const float* fcb    = (const float*)d_in[6];
  float* out = (float*)d_out;

  qconv_kernel<<<512, 256, 0, stream>>>(x, conv_w, conv_b, u3p, cu3p,
                                        fcw, fcb, out);
}

// Round 12
// 106.520 us; speedup vs baseline: 1.1183x; 1.0045x over previous
//
#include <hip/hip_runtime.h>

typedef float v2f __attribute__((ext_vector_type(2)));

// ---------------------------------------------------------------------------
// Cross-lane helpers: masks 1,2,3,8 via DPP (VALU pipe), mask 4 via
// ds_swizzle; ds_bpermute only for the one-time angle gather.
// ---------------------------------------------------------------------------
template<int C>
__device__ __forceinline__ float dppmov(float x) {
  return __int_as_float(__builtin_amdgcn_update_dpp(0, __float_as_int(x), C, 0xF, 0xF, true));
}
template<int IMM>
__device__ __forceinline__ float dswz(float x) {
  return __int_as_float(__builtin_amdgcn_ds_swizzle(__float_as_int(x), IMM));
}
__device__ __forceinline__ float bperm(float x, int a) {
  return __int_as_float(__builtin_amdgcn_ds_bpermute(a, __float_as_int(x)));
}
template<int M>
__device__ __forceinline__ float bfly(float x) {
  if constexpr (M == 1)      return dppmov<0xB1>(x);   // quad_perm [1,0,3,2]
  else if constexpr (M == 2) return dppmov<0x4E>(x);   // quad_perm [2,3,0,1]
  else if constexpr (M == 3) return dppmov<0x1B>(x);   // quad_perm [3,2,1,0]
  else if constexpr (M == 8) return dppmov<0x128>(x);  // row_ror:8 == xor8
  else                       return dswz<0x101F>(x);   // M==4: bit-mode xor4
}
template<int M>
__device__ __forceinline__ v2f bfly2(v2f v) {
  v2f o; o.x = bfly<M>(v.x); o.y = bfly<M>(v.y); return o;
}
__device__ __forceinline__ v2f sp(float s) { v2f v; v.x = s; v.y = s; return v; }
__device__ __forceinline__ v2f vfma(v2f a, v2f b, v2f c) {
  return __builtin_elementwise_fma(a, b, c);
}

// ---------------------------------------------------------------------------
// Layout: 8 pixels/wave. Group g = lane>>4 holds the packed pixel pair in v2f.
// Amp i = q*16 + r, q = lane&15, r = 0..15. Wires 0..3 <-> q bits 3..0
// (masks 8,4,2,1); wires 4..7 <-> r bits 3..0.
// ---------------------------------------------------------------------------
template<int M, int CM>
__device__ __forceinline__ void crossG(v2f Sr[16], v2f Si[16],
    const float* g, int lane) {
  const bool hi = (lane & M) != 0;
  float fr, fi, gr, gi;
  if constexpr (CM == 0) {
    fr = hi ? g[6] : g[0]; fi = hi ? g[7] : g[1];
    gr = hi ? g[4] : g[2]; gi = hi ? g[5] : g[3];
  } else {
    const bool ct = (lane & CM) != 0;
    float f0r = hi ? g[6]  : g[0],  f0i = hi ? g[7]  : g[1];
    float g0r = hi ? g[4]  : g[2],  g0i = hi ? g[5]  : g[3];
    float f1r = hi ? g[14] : g[8],  f1i = hi ? g[15] : g[9];
    float g1r = hi ? g[12] : g[10], g1i = hi ? g[13] : g[11];
    fr = ct ? f1r : f0r; fi = ct ? f1i : f0i;
    gr = ct ? g1r : g0r; gi = ct ? g1i : g0i;
  }
  v2f vfr = sp(fr), vfi = sp(fi), vgr = sp(gr), vgi = sp(gi);
  v2f vfiN = sp(-fi), vgiN = sp(-gi);
#pragma unroll
  for (int r = 0; r < 16; ++r) {
    v2f pR = bfly2<M>(Sr[r]);
    v2f pI = bfly2<M>(Si[r]);
    v2f nR = vfma(vgiN, pI, vfma(vgr, pR, vfma(vfiN, Si[r], vfr * Sr[r])));
    v2f nI = vfma(vgi,  pR, vfma(vgr, pI, vfma(vfi,  Sr[r], vfr * Si[r])));
    Sr[r] = nR; Si[r] = nI;
  }
}

__device__ __forceinline__ void mixP(v2f& x0r, v2f& x0i, v2f& x1r, v2f& x1i,
    float m0r, float m0i, float m1r, float m1i,
    float m2r, float m2i, float m3r, float m3i) {
  v2f n0r = vfma(sp(-m1i), x1i, vfma(sp(m1r), x1r, vfma(sp(-m0i), x0i, sp(m0r) * x0r)));
  v2f n0i = vfma(sp( m1i), x1r, vfma(sp(m1r), x1i, vfma(sp( m0i), x0r, sp(m0r) * x0i)));
  v2f n1r = vfma(sp(-m3i), x1i, vfma(sp(m3r), x1r, vfma(sp(-m2i), x0i, sp(m2r) * x0r)));
  v2f n1i = vfma(sp( m3i), x1r, vfma(sp(m3r), x1i, vfma(sp( m2i), x0r, sp(m2r) * x0i)));
  x0r = n0r; x0i = n0i; x1r = n1r; x1i = n1i;
}

// F23: fused (F3·F2) 4x4 on wires 2,3 (lane bits 1,0). Per-lane coefficient
// row from LDS: idx = (lane bit2 = F2's ctrl)<<2 | (lane&3); row holds
// c_k = T[row][row^k], k=0..3 (partners via DPP xor1/xor2/xor3).
__device__ __forceinline__ void f23N(v2f Sr[16], v2f Si[16],
    const float* tab, int lane) {
  const int idx = ((lane >> 2) & 1) * 4 + (lane & 3);
  const float* rp = tab + idx * 8;
  const float c0r = rp[0], c0i = rp[1], c1r = rp[2], c1i = rp[3];
  const float c2r = rp[4], c2i = rp[5], c3r = rp[6], c3i = rp[7];
#pragma unroll
  for (int r = 0; r < 16; ++r) {
    v2f p1R = bfly2<1>(Sr[r]), p1I = bfly2<1>(Si[r]);
    v2f p2R = bfly2<2>(Sr[r]), p2I = bfly2<2>(Si[r]);
    v2f p3R = bfly2<3>(Sr[r]), p3I = bfly2<3>(Si[r]);
    v2f nR = sp(c0r) * Sr[r];
    nR = vfma(sp(-c0i), Si[r], nR);
    nR = vfma(sp( c1r), p1R, nR);  nR = vfma(sp(-c1i), p1I, nR);
    nR = vfma(sp( c2r), p2R, nR);  nR = vfma(sp(-c2i), p2I, nR);
    nR = vfma(sp( c3r), p3R, nR);  nR = vfma(sp(-c3i), p3I, nR);
    v2f nI = sp(c0i) * Sr[r];
    nI = vfma(sp(c0r), Si[r], nI);
    nI = vfma(sp(c1i), p1R, nI);   nI = vfma(sp(c1r), p1I, nI);
    nI = vfma(sp(c2i), p2R, nI);   nI = vfma(sp(c2r), p2I, nI);
    nI = vfma(sp(c3i), p3R, nI);   nI = vfma(sp(c3r), p3I, nI);
    Sr[r] = nR; Si[r] = nI;
  }
}

// F4: fused u3(w4)+cu3(3->4): ctrl lane bit0 (wire 3), target r bit3.
__device__ __forceinline__ void f4N(v2f Sr[16], v2f Si[16],
    const float* g, int lane) {
  const bool ct = (lane & 1) != 0;
  float m[8];
#pragma unroll
  for (int jj = 0; jj < 8; ++jj) m[jj] = ct ? g[8 + jj] : g[jj];
#pragma unroll
  for (int r = 0; r < 8; ++r)
    mixP(Sr[r], Si[r], Sr[r + 8], Si[r + 8],
         m[0], m[1], m[2], m[3], m[4], m[5], m[6], m[7]);
}
// F5: ctrl r bit3, target r bit2.
__device__ __forceinline__ void f5N(v2f Sr[16], v2f Si[16], const float* g) {
#pragma unroll
  for (int r = 0; r < 4; ++r)
    mixP(Sr[r], Si[r], Sr[r + 4], Si[r + 4],
         g[0], g[1], g[2], g[3], g[4], g[5], g[6], g[7]);
#pragma unroll
  for (int r = 8; r < 12; ++r)
    mixP(Sr[r], Si[r], Sr[r + 4], Si[r + 4],
         g[8], g[9], g[10], g[11], g[12], g[13], g[14], g[15]);
}
// F67: fused (F7·F6) 4x4 per reg-quad (r bits 1,0); matrix by quad's r bit2.
// T row-major 4x4 complex: out[r'] = sum_c T[r'][c] * amp[B+c].
__device__ __forceinline__ void f67N(v2f Sr[16], v2f Si[16], const float* T) {
#pragma unroll
  for (int qd = 0; qd < 4; ++qd) {
    const int B = qd * 4;
    const float* M = T + (qd & 1) * 32;
    v2f ar0 = Sr[B+0], ai0 = Si[B+0], ar1 = Sr[B+1], ai1 = Si[B+1];
    v2f ar2 = Sr[B+2], ai2 = Si[B+2], ar3 = Sr[B+3], ai3 = Si[B+3];
#pragma unroll
    for (int rp = 0; rp < 4; ++rp) {
      const float* Mr = M + rp * 8;
      v2f nR = sp(Mr[0]) * ar0;
      nR = vfma(sp(-Mr[1]), ai0, nR);
      nR = vfma(sp( Mr[2]), ar1, nR);
      nR = vfma(sp(-Mr[3]), ai1, nR);
      nR = vfma(sp( Mr[4]), ar2, nR);
      nR = vfma(sp(-Mr[5]), ai2, nR);
      nR = vfma(sp( Mr[6]), ar3, nR);
      nR = vfma(sp(-Mr[7]), ai3, nR);
      v2f nI = sp(Mr[1]) * ar0;
      nI = vfma(sp(Mr[0]), ai0, nI);
      nI = vfma(sp(Mr[3]), ar1, nI);
      nI = vfma(sp(Mr[2]), ai1, nI);
      nI = vfma(sp(Mr[5]), ar2, nI);
      nI = vfma(sp(Mr[4]), ai2, nI);
      nI = vfma(sp(Mr[7]), ar3, nI);
      nI = vfma(sp(Mr[6]), ai3, nI);
      Sr[B + rp] = nR; Si[B + rp] = nI;
    }
  }
}
// F8': fused cu3(7->0)+next u3(w0): ctrl r bit0, target mask 8.
__device__ __forceinline__ void f8pN(v2f Sr[16], v2f Si[16],
    const float* g, int lane) {
  const bool hi = (lane & 8) != 0;
  float fr[2], fi[2], gr[2], gi[2];
  fr[0] = hi ? g[6]  : g[0];  fi[0] = hi ? g[7]  : g[1];
  gr[0] = hi ? g[4]  : g[2];  gi[0] = hi ? g[5]  : g[3];
  fr[1] = hi ? g[14] : g[8];  fi[1] = hi ? g[15] : g[9];
  gr[1] = hi ? g[12] : g[10]; gi[1] = hi ? g[13] : g[11];
#pragma unroll
  for (int r = 0; r < 16; ++r) {
    const int m = r & 1;
    v2f pR = bfly2<8>(Sr[r]);
    v2f pI = bfly2<8>(Si[r]);
    v2f nR = vfma(sp(-gi[m]), pI, vfma(sp(gr[m]), pR, vfma(sp(-fi[m]), Si[r], sp(fr[m]) * Sr[r])));
    v2f nI = vfma(sp( gi[m]), pR, vfma(sp(gr[m]), pI, vfma(sp( fi[m]), Sr[r], sp(fr[m]) * Si[r])));
    Sr[r] = nR; Si[r] = nI;
  }
}
// F8 final standalone cu3(7->0): odd r only, target mask 8.
__device__ __forceinline__ void f8N(v2f Sr[16], v2f Si[16],
    const float* g, int lane) {
  const bool hi = (lane & 8) != 0;
  const float fr = hi ? g[6] : g[0], fi = hi ? g[7] : g[1];
  const float gr = hi ? g[4] : g[2], gi = hi ? g[5] : g[3];
#pragma unroll
  for (int r = 1; r < 16; r += 2) {
    v2f pR = bfly2<8>(Sr[r]);
    v2f pI = bfly2<8>(Si[r]);
    v2f nR = vfma(sp(-gi), pI, vfma(sp(gr), pR, vfma(sp(-fi), Si[r], sp(fr) * Sr[r])));
    v2f nI = vfma(sp( gi), pR, vfma(sp(gr), pI, vfma(sp( fi), Sr[r], sp(fr) * Si[r])));
    Sr[r] = nR; Si[r] = nI;
  }
}

// Off-diagonal pair sum for a cross wire (mask M): per-lane partials.
template<int M>
__device__ __forceinline__ void crossO(const v2f Sr[16], const v2f Si[16],
                                       v2f& re, v2f& im) {
  v2f r = sp(0.0f), i = sp(0.0f);
#pragma unroll
  for (int k = 0; k < 16; ++k) {
    v2f pr = bfly2<M>(Sr[k]);
    v2f pi = bfly2<M>(Si[k]);
    r = vfma(Sr[k], pr, r);
    r = vfma(Si[k], pi, r);
    i = vfma(Si[k], pr, i);
    i = vfma(-Sr[k], pi, i);
  }
  re = r; im = i;
}

// ---------------------------------------------------------------------------
// Prep helpers.
// ---------------------------------------------------------------------------
__device__ __forceinline__ void mm2(const float* A, const float* B, float* D) {
  D[0] = A[0]*B[0] - A[1]*B[1] + A[2]*B[4] - A[3]*B[5];
  D[1] = A[0]*B[1] + A[1]*B[0] + A[2]*B[5] + A[3]*B[4];
  D[2] = A[0]*B[2] - A[1]*B[3] + A[2]*B[6] - A[3]*B[7];
  D[3] = A[0]*B[3] + A[1]*B[2] + A[2]*B[7] + A[3]*B[6];
  D[4] = A[4]*B[0] - A[5]*B[1] + A[6]*B[4] - A[7]*B[5];
  D[5] = A[4]*B[1] + A[5]*B[0] + A[6]*B[5] + A[7]*B[4];
  D[6] = A[4]*B[2] - A[5]*B[3] + A[6]*B[6] - A[7]*B[7];
  D[7] = A[4]*B[3] + A[5]*B[2] + A[6]*B[7] + A[7]*B[6];
}
__device__ __forceinline__ void u3fill(const float* src, float* o) {
  float th = src[0], ph = src[1], lam = src[2];
  float c = cosf(0.5f * th), s = sinf(0.5f * th);
  float cl = cosf(lam), sl = sinf(lam);
  float cp = cosf(ph), spv = sinf(ph);
  float cpl = cosf(ph + lam), spl = sinf(ph + lam);
  o[0] = c;        o[1] = 0.0f;
  o[2] = -cl * s;  o[3] = -sl * s;
  o[4] = cp * s;   o[5] = spv * s;
  o[6] = cpl * c;  o[7] = spl * c;
}

// ---------------------------------------------------------------------------
// Single fused kernel: in-LDS prep (G table + fused 4x4 tables + FC weights),
// then conv + qsim (31 serial gate stages) + direct-Pauli measurement + FC.
// ---------------------------------------------------------------------------
__global__ __launch_bounds__(256) void qconv_kernel(
    const float* __restrict__ x, const float* __restrict__ cw,
    const float* __restrict__ cb, const float* __restrict__ u3p,
    const float* __restrict__ cu3p, const float* __restrict__ fcw,
    const float* __restrict__ fcb, float* __restrict__ out) {
  __shared__ float Us[40][8];
  __shared__ float Cs[40][8];
  __shared__ float Gs[640];
  __shared__ float FCWs[768];
  __shared__ float F23t[320];   // 5 blocks x 8 rows x 8 floats
  __shared__ float F67t[320];   // 5 blocks x 2 matrices x 16 complex

  // ---- in-block prep ----
  {
    const int t = threadIdx.x;
    if (t < 40) u3fill(u3p + t * 3, Us[t]);
    if (t >= 64 && t < 104) u3fill(cu3p + (t - 64) * 3, Cs[t - 64]);
    for (int i = t; i < 768; i += 256) {
      int tt = i % 24;
      int stage = tt >> 3, w = tt & 7;
      float sc = (stage >= 1 && w >= 4) ? 2.0f : 1.0f;
      FCWs[i] = fcw[i] * sc;
    }
    __syncthreads();
    if (t == 0) {
#pragma unroll
      for (int j = 0; j < 8; ++j) Gs[j] = Us[0][j];
    } else if (t < 36) {
      int j = t - 1, b = j / 7, k = j % 7;
      float* dst = Gs + 8 + b * 112 + k * 16;
      const float* U = Us[b * 8 + k + 1];
      const float* C = Cs[b * 8 + k];
#pragma unroll
      for (int u = 0; u < 8; ++u) dst[u] = U[u];
      mm2(C, U, dst + 8);
    } else if (t < 40) {
      int b = t - 36;
      float* dst = Gs + 568 + b * 16;
      const float* U = Us[(b + 1) * 8];
      const float* C = Cs[b * 8 + 7];
#pragma unroll
      for (int u = 0; u < 8; ++u) dst[u] = U[u];
      mm2(U, C, dst + 8);
    } else if (t == 40) {
#pragma unroll
      for (int j = 0; j < 8; ++j) Gs[632 + j] = Cs[39][j];
    }
    __syncthreads();
    // fused 4x4 tables from Gs
    if (t < 40) {
      // F23: T_ct[row][col] = M2_ct[w2'][w2] * M3_{w2'}[w3'][w3]
      int b = t >> 3, idx = t & 7;
      int ct = idx >> 2, row = idx & 3;
      const float* M2 = Gs + 8 + b * 112 + 16 + ct * 8;
      int w2p = row >> 1, w3p = row & 1;
      const float* M3 = Gs + 8 + b * 112 + 32 + w2p * 8;
      float* dst = F23t + b * 64 + idx * 8;
#pragma unroll
      for (int k = 0; k < 4; ++k) {
        int w2 = w2p ^ (k >> 1), w3 = w3p ^ (k & 1);
        float a_r = M2[(w2p * 2 + w2) * 2], a_i = M2[(w2p * 2 + w2) * 2 + 1];
        float b_r = M3[(w3p * 2 + w3) * 2], b_i = M3[(w3p * 2 + w3) * 2 + 1];
        dst[k * 2]     = a_r * b_r - a_i * b_i;
        dst[k * 2 + 1] = a_r * b_i + a_i * b_r;
      }
    } else if (t >= 64 && t < 104) {
      // F67: T_ct[r'][c] = M6_ct[b1'][b1] * M7_{b1'}[b0'][b0]
      int u = t - 64;
      int b = u >> 3, idx = u & 7;
      int ct = idx >> 2, rp = idx & 3;
      const float* M6 = Gs + 8 + b * 112 + 80 + ct * 8;
      int b1p = rp >> 1, b0p = rp & 1;
      const float* M7 = Gs + 8 + b * 112 + 96 + b1p * 8;
      float* dst = F67t + b * 64 + ct * 32 + rp * 8;
#pragma unroll
      for (int c = 0; c < 4; ++c) {
        int b1 = c >> 1, b0 = c & 1;
        float a_r = M6[(b1p * 2 + b1) * 2], a_i = M6[(b1p * 2 + b1) * 2 + 1];
        float b_r = M7[(b0p * 2 + b0) * 2], b_i = M7[(b0p * 2 + b0) * 2 + 1];
        dst[c * 2]     = a_r * b_r - a_i * b_i;
        dst[c * 2 + 1] = a_r * b_i + a_i * b_r;
      }
    }
    __syncthreads();
  }

  const int lane = threadIdx.x & 63;
  const int wid = __builtin_amdgcn_readfirstlane(
      (int)((blockIdx.x * blockDim.x + threadIdx.x) >> 6));
  const int p0 = wid * 8;
  const int q = lane & 15;

  // ---- conv: lane = (px = lane>>3, oc = lane&7) ----
  float ang;
  {
    const int px = lane >> 3;
    const int oc = lane & 7;
    const int p  = p0 + px;
    const int b  = p >> 12;
    const int hh = (p >> 6) & 63;
    const int wim = p & 63;
    float acc = cb[oc];
#pragma unroll 4
    for (int ic = 0; ic < 16; ++ic) {
      const float* wp = cw + (oc * 16 + ic) * 9;
      const float* xp = x + (b * 16 + ic) * 4096;
#pragma unroll
      for (int kh = 0; kh < 3; ++kh) {
        int ih = hh + kh - 1;
        bool rok = (unsigned)ih < 64u;
        int ihc = rok ? ih : 0;
#pragma unroll
        for (int kw = 0; kw < 3; ++kw) {
          int iw = wim + kw - 1;
          bool ok = rok && ((unsigned)iw < 64u);
          int iwc = ((unsigned)iw < 64u) ? iw : 0;
          float xv = xp[ihc * 64 + iwc];
          acc = fmaf(ok ? xv : 0.0f, wp[kh * 3 + kw], acc);
        }
      }
    }
    ang = acc;
  }

  // ---- gather 16 angles, build product state with F0 folded ----
  v2f Sr[16], Si[16];
  {
    const int gb = (lane & 48) << 2;
    float aA[8], aB[8];
#pragma unroll
    for (int w = 0; w < 8; ++w) {
      aA[w] = bperm(ang, gb + (w << 2));
      aB[w] = bperm(ang, gb + ((8 + w) << 2));
    }
    float cA[8], sA[8], cB[8], sB[8];
#pragma unroll
    for (int w = 0; w < 8; ++w) {
      __sincosf(0.5f * aA[w], &sA[w], &cA[w]);
      __sincosf(0.5f * aB[w], &sB[w], &cB[w]);
    }
    v2f c0; c0.x = cA[0]; c0.y = cB[0];
    v2f s0; s0.x = sA[0]; s0.y = sB[0];
    v2f c0r = vfma(sp(Gs[2]), s0, sp(Gs[0]) * c0);
    v2f c0i = vfma(sp(Gs[3]), s0, sp(Gs[1]) * c0);
    v2f s0r = vfma(sp(Gs[6]), s0, sp(Gs[4]) * c0);
    v2f s0i = vfma(sp(Gs[7]), s0, sp(Gs[5]) * c0);
    const bool w0 = (q & 8) != 0;
    v2f selR = w0 ? s0r : c0r;
    v2f selI = w0 ? s0i : c0i;
    float fA = ((q & 4) ? sA[1] : cA[1]) * ((q & 2) ? sA[2] : cA[2])
             * ((q & 1) ? sA[3] : cA[3]);
    float fB = ((q & 4) ? sB[1] : cB[1]) * ((q & 2) ? sB[2] : cB[2])
             * ((q & 1) ? sB[3] : cB[3]);
    v2f uu[4], vv[4];
    uu[0].x = cA[6]*cA[7]; uu[1].x = cA[6]*sA[7];
    uu[2].x = sA[6]*cA[7]; uu[3].x = sA[6]*sA[7];
    uu[0].y = cB[6]*cB[7]; uu[1].y = cB[6]*sB[7];
    uu[2].y = sB[6]*cB[7]; uu[3].y = sB[6]*sB[7];
    float vA0 = fA * cA[4], vA1 = fA * sA[4];
    float vB0 = fB * cB[4], vB1 = fB * sB[4];
    vv[0].x = vA0*cA[5]; vv[1].x = vA0*sA[5];
    vv[2].x = vA1*cA[5]; vv[3].x = vA1*sA[5];
    vv[0].y = vB0*cB[5]; vv[1].y = vB0*sB[5];
    vv[2].y = vB1*cB[5]; vv[3].y = vB1*sB[5];
#pragma unroll
    for (int r = 0; r < 16; ++r) {
      v2f base = vv[r >> 2] * uu[r & 3];
      Sr[r] = selR * base;
      Si[r] = selI * base;
    }
  }

  // ---- fused circuit (F0 in init; F23/F67 fused -> 31 serial stages) ----
  for (int b = 0; b < 5; ++b) {
    const float* base = Gs + 8 + b * 112;
    crossG<4, 8>(Sr, Si, base + 0, lane);
    f23N(Sr, Si, F23t + b * 64, lane);
    f4N(Sr, Si, base + 48, lane);
    f5N(Sr, Si, base + 64);
    f67N(Sr, Si, F67t + b * 64);
    if (b < 4) f8pN(Sr, Si, Gs + 568 + b * 16, lane);
  }
  f8N(Sr, Si, Gs + 632, lane);

  // ---- per-lane measurement partials ----
  float sg[4];
  sg[0] = (q & 8) ? -1.0f : 1.0f;
  sg[1] = (q & 4) ? -1.0f : 1.0f;
  sg[2] = (q & 2) ? -1.0f : 1.0f;
  sg[3] = (q & 1) ? -1.0f : 1.0f;

  v2f PT[24];
  {
    v2f re0, im0, re1, im1, re2, im2, re3, im3;
    crossO<8>(Sr, Si, re0, im0);
    crossO<4>(Sr, Si, re1, im1);
    crossO<2>(Sr, Si, re2, im2);
    crossO<1>(Sr, Si, re3, im3);
    PT[8]  = re0; PT[9]  = re1; PT[10] = re2; PT[11] = re3;
    PT[16] = sp(sg[0]) * im0; PT[17] = sp(sg[1]) * im1;
    PT[18] = sp(sg[2]) * im2; PT[19] = sp(sg[3]) * im3;

    v2f P[16];
#pragma unroll
    for (int r = 0; r < 16; ++r) P[r] = vfma(Si[r], Si[r], Sr[r] * Sr[r]);
    v2f t01[8];
#pragma unroll
    for (int k = 0; k < 8; ++k) t01[k] = P[2*k] + P[2*k+1];
    v2f q0 = t01[0] + t01[1], q1 = t01[2] + t01[3];
    v2f q2 = t01[4] + t01[5], q3 = t01[6] + t01[7];
    v2f h0 = q0 + q1, h1 = q2 + q3;
    v2f p  = h0 + h1;
    PT[4] = h0 - h1;
    PT[5] = (q0 - q1) + (q2 - q3);
    PT[6] = (t01[0]-t01[1]) + (t01[2]-t01[3])
          + (t01[4]-t01[5]) + (t01[6]-t01[7]);
    PT[7] = (P[0]-P[1]) + (P[2]-P[3]) + (P[4]-P[5]) + (P[6]-P[7])
          + (P[8]-P[9]) + (P[10]-P[11]) + (P[12]-P[13]) + (P[14]-P[15]);
    PT[0] = sp(sg[0]) * p; PT[1] = sp(sg[1]) * p;
    PT[2] = sp(sg[2]) * p; PT[3] = sp(sg[3]) * p;

    v2f re, im;
    re = sp(0.0f); im = sp(0.0f);
#pragma unroll
    for (int r = 0; r < 8; ++r) {
      re = vfma(Sr[r], Sr[r+8], re); re = vfma(Si[r], Si[r+8], re);
      im = vfma(Si[r], Sr[r+8], im); im = vfma(-Sr[r], Si[r+8], im);
    }
    PT[12] = re; PT[20] = im;
    re = sp(0.0f); im = sp(0.0f);
#pragma unroll
    for (int t = 0; t < 8; ++t) {
      const int lo = (t & 3) + (t >> 2) * 8;
      re = vfma(Sr[lo], Sr[lo+4], re); re = vfma(Si[lo], Si[lo+4], re);
      im = vfma(Si[lo], Sr[lo+4], im); im = vfma(-Sr[lo], Si[lo+4], im);
    }
    PT[13] = re; PT[21] = im;
    re = sp(0.0f); im = sp(0.0f);
#pragma unroll
    for (int t = 0; t < 8; ++t) {
      const int lo = (t & 1) + (t >> 1) * 4;
      re = vfma(Sr[lo], Sr[lo+2], re); re = vfma(Si[lo], Si[lo+2], re);
      im = vfma(Si[lo], Sr[lo+2], im); im = vfma(-Sr[lo], Si[lo+2], im);
    }
    PT[14] = re; PT[22] = im;
    re = sp(0.0f); im = sp(0.0f);
#pragma unroll
    for (int t = 0; t < 8; ++t) {
      const int lo = 2 * t;
      re = vfma(Sr[lo], Sr[lo+1], re); re = vfma(Si[lo], Si[lo+1], re);
      im = vfma(Si[lo], Sr[lo+1], im); im = vfma(-Sr[lo], Si[lo+1], im);
    }
    PT[15] = re; PT[23] = im;
  }

  // ---- group-reduce partials to uniform values, THEN per-channel FC ----
  const int j = q & 7;
  const bool isB = (q & 8) != 0;
  float mm[24];
#pragma unroll
  for (int t = 0; t < 24; ++t) {
    v2f v = PT[t] + bfly2<8>(PT[t]);   // pair over mask 8 (both pixels)
    float s = isB ? v.y : v.x;          // keep own pixel
    s += bfly<1>(s);
    s += bfly<2>(s);
    s += bfly<4>(s);                    // completes the 16-lane sum
    mm[t] = s;
  }

  const int g = lane >> 4;
  const int p = p0 + 2 * g + (isB ? 1 : 0);
  const int ob = (p >> 12) * 131072 + (p & 4095);
#pragma unroll
  for (int k = 0; k < 4; ++k) {
    const int ch = 4 * j + k;
    const float* wr = FCWs + ch * 24;
    float acc = fcb[ch];
#pragma unroll
    for (int u = 0; u < 24; ++u) acc = fmaf(mm[u], wr[u], acc);
    out[ob + ch * 4096] = acc;
  }
}

extern "C" void kernel_launch(void* const* d_in, const int* in_sizes, int n_in,
                              void* d_out, int out_size, void* d_ws, size_t ws_size,
                              hipStream_t stream) {
  const float* x      = (const float*)d_in[0];
  const float* conv_w = (const float*)d_in[1];
  const float* conv_b = (const float*)d_in[2];
  const float* u3p    = (const float*)d_in[3];
  const float* cu3p   = (const float*)d_in[4];
  const float* fcw    = (const float*)d_in[5];
  const float* fcb    = (const float*)d_in[6];
  float* out = (float*)d_out;

  qconv_kernel<<<512, 256, 0, stream>>>(x, conv_w, conv_b, u3p, cu3p,
                                        fcw, fcb, out);
}